// Round 3
// baseline (880.285 us; speedup 1.0000x reference)
//
#include <hip/hip_runtime.h>

#define BB  4
#define SEQ 2048
#define DIM 512
#define DK  64

// Tiled f32 GEMM: C[m,n] = scale * sum_k A[m,k]*B[k,n] (+resid) (mask==0 -> -1e9)
// TM=128, TN=64*NGRP, TK=32. 256 threads, micro-tile 2x{4} rows x NGRPx{4} cols.
template<bool BTRANS, bool MASKED, bool RESID, int NGRP>
__global__ __launch_bounds__(256) void gemm_kernel(
    const float* __restrict__ A, const float* __restrict__ Bm, float* __restrict__ C,
    const float* __restrict__ resid, const int* __restrict__ mask,
    int K, int lda, int ldb, int ldc,
    long sA, long sB, long sC, long sR, long sM, float scale)
{
  constexpr int TM = 128, TK = 32, TN = 64*NGRP;
  __shared__ float As[TK][TM+4];
  __shared__ float Bs[TK][TN+4];
  const int z = blockIdx.z;
  A += z*sA; Bm += z*sB; C += z*sC;
  const float* rp = nullptr; const int* mp = nullptr;
  if constexpr (RESID)  rp = resid + z*sR;
  if constexpr (MASKED) mp = mask  + z*sM;
  const int m0 = blockIdx.x*TM, n0 = blockIdx.y*TN;
  const int tid = threadIdx.x, tx = tid & 15, ty = tid >> 4;
  float acc[2][NGRP][4][4] = {};

  for (int k0 = 0; k0 < K; k0 += TK) {
    // A tile: [TM x TK] -> As[kk][m], float4 along k
    #pragma unroll
    for (int e = tid; e < TM*TK/4; e += 256) {
      int m = e >> 3, k4 = (e & 7) << 2;
      float4 a = *(const float4*)&A[(long)(m0+m)*lda + k0 + k4];
      As[k4+0][m] = a.x; As[k4+1][m] = a.y; As[k4+2][m] = a.z; As[k4+3][m] = a.w;
    }
    if constexpr (BTRANS) {
      // B is [N x K] row-major: float4 along k, scatter to Bs[kk][n]
      #pragma unroll
      for (int e = tid; e < TN*TK/4; e += 256) {
        int n = e >> 3, k4 = (e & 7) << 2;
        float4 b = *(const float4*)&Bm[(long)(n0+n)*ldb + k0 + k4];
        Bs[k4+0][n] = b.x; Bs[k4+1][n] = b.y; Bs[k4+2][n] = b.z; Bs[k4+3][n] = b.w;
      }
    } else {
      // B is [K x N] row-major: float4 along n
      constexpr int TN4 = TN/4;
      #pragma unroll
      for (int e = tid; e < TK*TN4; e += 256) {
        int kk = e / TN4, n4 = (e % TN4) << 2;
        *(float4*)&Bs[kk][n4] = *(const float4*)&Bm[(long)(k0+kk)*ldb + n0 + n4];
      }
    }
    __syncthreads();
    #pragma unroll
    for (int kk = 0; kk < TK; kk++) {
      float av[2][4];
      float bv[NGRP][4];
      *(float4*)av[0] = *(const float4*)&As[kk][ty*4];
      *(float4*)av[1] = *(const float4*)&As[kk][64 + ty*4];
      #pragma unroll
      for (int g = 0; g < NGRP; g++)
        *(float4*)bv[g] = *(const float4*)&Bs[kk][g*64 + tx*4];
      #pragma unroll
      for (int mg = 0; mg < 2; mg++)
        #pragma unroll
        for (int r = 0; r < 4; r++)
          #pragma unroll
          for (int g = 0; g < NGRP; g++)
            #pragma unroll
            for (int c = 0; c < 4; c++)
              acc[mg][g][r][c] = fmaf(av[mg][r], bv[g][c], acc[mg][g][r][c]);
    }
    __syncthreads();
  }

  #pragma unroll
  for (int mg = 0; mg < 2; mg++) {
    #pragma unroll
    for (int r = 0; r < 4; r++) {
      const int m = m0 + mg*64 + ty*4 + r;
      #pragma unroll
      for (int g = 0; g < NGRP; g++) {
        const int n = n0 + g*64 + tx*4;
        float4 v;
        v.x = acc[mg][g][r][0]*scale; v.y = acc[mg][g][r][1]*scale;
        v.z = acc[mg][g][r][2]*scale; v.w = acc[mg][g][r][3]*scale;
        if constexpr (RESID) {
          float4 rv = *(const float4*)&rp[(long)m*ldc + n];
          v.x += rv.x; v.y += rv.y; v.z += rv.z; v.w += rv.w;
        }
        if constexpr (MASKED) {
          int4 mv = *(const int4*)&mp[(long)m*ldc + n];
          if (!mv.x) v.x = -1e9f;
          if (!mv.y) v.y = -1e9f;
          if (!mv.z) v.z = -1e9f;
          if (!mv.w) v.w = -1e9f;
        }
        *(float4*)&C[(long)m*ldc + n] = v;
      }
    }
  }
}

// One block per score row of 2048 f32: in-place softmax (GAMMA = 1).
__global__ __launch_bounds__(256) void softmax_kernel(float* __restrict__ attn)
{
  const long row = blockIdx.x;
  float* p = attn + row*SEQ;
  const int t = threadIdx.x;
  float4 a = ((const float4*)p)[t];
  float4 b = ((const float4*)p)[t + 256];
  float f[8] = {a.x,a.y,a.z,a.w,b.x,b.y,b.z,b.w};
  float M = f[0];
  #pragma unroll
  for (int i = 1; i < 8; i++) M = fmaxf(M, f[i]);
  #pragma unroll
  for (int o = 1; o < 64; o <<= 1) M = fmaxf(M, __shfl_xor(M, o));
  __shared__ float r1[4], r2[4];
  if ((t & 63) == 0) r1[t >> 6] = M;
  __syncthreads();
  M = fmaxf(fmaxf(r1[0], r1[1]), fmaxf(r1[2], r1[3]));
  float s = 0.f;
  #pragma unroll
  for (int i = 0; i < 8; i++) { f[i] = __expf(f[i] - M); s += f[i]; }
  #pragma unroll
  for (int o = 1; o < 64; o <<= 1) s += __shfl_xor(s, o);
  if ((t & 63) == 0) r2[t >> 6] = s;
  __syncthreads();
  s = (r2[0] + r2[1]) + (r2[2] + r2[3]);
  const float inv = 1.0f / s;
  a.x = f[0]*inv; a.y = f[1]*inv; a.z = f[2]*inv; a.w = f[3]*inv;
  b.x = f[4]*inv; b.y = f[5]*inv; b.z = f[6]*inv; b.w = f[7]*inv;
  ((float4*)p)[t] = a;
  ((float4*)p)[t + 256] = b;
}

// Fused fc + LayerNorm, IN PLACE on X[8192,512]: each block owns 32 full rows.
// Y = LN(X_rows @ W). In-place safe: block reads only its own rows, writes same rows.
// Thread layout: tx=tid&63 (8 cols each, 64 lanes cover 512 cols = one wave per
// row-group), ty=tid>>6 (8 rows each). LN reduction = wave-wide __shfl_xor.
__global__ __launch_bounds__(256) void fc_ln_kernel(
    float* __restrict__ X, const float* __restrict__ W,
    const float* __restrict__ g, const float* __restrict__ b)
{
  __shared__ float As[32][32+4];     // [k][m]
  __shared__ float Bs[32][512+4];    // [k][n]
  const int tid = threadIdx.x;
  const long r0 = (long)blockIdx.x * 32;
  const int tx = tid & 63, ty = tid >> 6;
  float acc[8][8] = {};

  for (int k0 = 0; k0 < DIM; k0 += 32) {
    { // A tile: 32 rows x 32 k = 1024 floats, one float4 per thread (along k)
      int m = tid >> 3, k4 = (tid & 7) << 2;
      float4 a = *(const float4*)&X[(r0+m)*DIM + k0 + k4];
      As[k4+0][m] = a.x; As[k4+1][m] = a.y; As[k4+2][m] = a.z; As[k4+3][m] = a.w;
    }
    // B tile: 32 k x 512 n = 16384 floats, 16 float4 per thread (along n)
    #pragma unroll
    for (int e = tid; e < 32*128; e += 256) {
      int kk = e >> 7, n4 = (e & 127) << 2;
      *(float4*)&Bs[kk][n4] = *(const float4*)&W[(long)(k0+kk)*DIM + n4];
    }
    __syncthreads();
    #pragma unroll
    for (int kk = 0; kk < 32; kk++) {
      float a[8], bb[8];
      *(float4*)&a[0]  = *(const float4*)&As[kk][ty*8];
      *(float4*)&a[4]  = *(const float4*)&As[kk][ty*8+4];
      *(float4*)&bb[0] = *(const float4*)&Bs[kk][tx*8];
      *(float4*)&bb[4] = *(const float4*)&Bs[kk][tx*8+4];
      #pragma unroll
      for (int r = 0; r < 8; r++)
        #pragma unroll
        for (int c = 0; c < 8; c++)
          acc[r][c] = fmaf(a[r], bb[c], acc[r][c]);
    }
    __syncthreads();
  }

  float gv[8], bv[8];
  *(float4*)&gv[0] = *(const float4*)&g[tx*8];
  *(float4*)&gv[4] = *(const float4*)&g[tx*8+4];
  *(float4*)&bv[0] = *(const float4*)&b[tx*8];
  *(float4*)&bv[4] = *(const float4*)&b[tx*8+4];

  #pragma unroll
  for (int r = 0; r < 8; r++) {
    float s = 0.f, sq = 0.f;
    #pragma unroll
    for (int c = 0; c < 8; c++) { s += acc[r][c]; sq += acc[r][c]*acc[r][c]; }
    #pragma unroll
    for (int o = 1; o < 64; o <<= 1) { s += __shfl_xor(s, o); sq += __shfl_xor(sq, o); }
    const float mean = s * (1.0f/DIM);
    float var = sq * (1.0f/DIM) - mean*mean;
    var = fmaxf(var, 0.0f);
    const float rs = rsqrtf(var + 1e-6f);
    float o0[8];
    #pragma unroll
    for (int c = 0; c < 8; c++) o0[c] = (acc[r][c] - mean)*rs*gv[c] + bv[c];
    float* dst = &X[(r0 + ty*8 + r)*DIM + tx*8];
    *(float4*)&dst[0] = *(const float4*)&o0[0];
    *(float4*)&dst[4] = *(const float4*)&o0[4];
  }
}

extern "C" void kernel_launch(void* const* d_in, const int* in_sizes, int n_in,
                              void* d_out, int out_size, void* d_ws, size_t ws_size,
                              hipStream_t stream) {
  const float* q    = (const float*)d_in[0];
  const float* k    = (const float*)d_in[1];
  const float* v    = (const float*)d_in[2];
  const int*   mask = (const int*)d_in[3];
  const float* w_qs = (const float*)d_in[4];
  const float* w_ks = (const float*)d_in[5];
  const float* w_fc = (const float*)d_in[6];
  const float* ln_g = (const float*)d_in[7];
  const float* ln_b = (const float*)d_in[8];

  float* out   = (float*)d_out;                       // [B,N,DIM] = 16.8MB
  float* attnF = out + (long)BB*SEQ*DIM;              // [B,N,N]: scores -> softmax in place

  // ZERO d_ws usage. Scratch lives inside d_out:
  //   qp/kp occupy the first 4MB of the out region (dead after pass 3);
  //   out1 = attn@v+v overwrites the full out region (pass 5);
  //   fc+LN runs in place on the out region (row-block-local).
  float* qp = out;
  float* kp = out + (long)BB*SEQ*DK;

  const long NN2 = (long)SEQ*SEQ;
  const long ND  = (long)SEQ*DIM;
  const long NK  = (long)SEQ*DK;

  // 1) qp = (q @ w_qs) / 8
  gemm_kernel<false,false,false,1><<<dim3(BB*SEQ/128,1,1), 256, 0, stream>>>(
      q, w_qs, qp, nullptr, nullptr, DIM, DIM, DK, DK, 0,0,0,0,0, 0.125f);
  // 2) kp = k @ w_ks
  gemm_kernel<false,false,false,1><<<dim3(BB*SEQ/128,1,1), 256, 0, stream>>>(
      k, w_ks, kp, nullptr, nullptr, DIM, DIM, DK, DK, 0,0,0,0,0, 1.0f);
  // 3) scores[b] = qp[b] @ kp[b]^T, mask==0 -> -1e9, into d_out attn region
  gemm_kernel<true,true,false,2><<<dim3(SEQ/128,SEQ/128,BB), 256, 0, stream>>>(
      qp, kp, attnF, nullptr, mask, DK, DK, DK, SEQ, NK, NK, NN2, 0, NN2, 1.0f);
  // 4) softmax in place
  softmax_kernel<<<dim3(BB*SEQ,1,1), 256, 0, stream>>>(attnF);
  // 5) out1[b] = attn[b] @ v[b] + v[b]  -> overwrites out region (qp/kp dead)
  gemm_kernel<false,false,true,2><<<dim3(SEQ/128,DIM/128,BB), 256, 0, stream>>>(
      attnF, v, out, v, nullptr, SEQ, SEQ, DIM, DIM, NN2, ND, ND, ND, 0, 1.0f);
  // 6+7) out = LayerNorm(out @ w_fc), fused, in place on out region
  fc_ln_kernel<<<dim3(BB*SEQ/32,1,1), 256, 0, stream>>>(out, w_fc, ln_g, ln_b);
}

// Round 4
// 602.722 us; speedup vs baseline: 1.4605x; 1.4605x over previous
//
#include <hip/hip_runtime.h>
#include <hip/hip_bf16.h>

#define BB  4
#define SEQ 2048
#define DIM 512
#define DK  64

typedef __attribute__((ext_vector_type(8))) short short8;
typedef __attribute__((ext_vector_type(4))) float f32x4;

__device__ __forceinline__ unsigned int pack_bf2(float a, float b){
  __hip_bfloat16 ha = __float2bfloat16(a), hb = __float2bfloat16(b);
  unsigned short ua = __builtin_bit_cast(unsigned short, ha);
  unsigned short ub = __builtin_bit_cast(unsigned short, hb);
  return (unsigned int)ua | ((unsigned int)ub << 16);
}
__device__ __forceinline__ unsigned short to_bf(float a){
  return __builtin_bit_cast(unsigned short, __float2bfloat16(a));
}

// ---------------- Tiled f32 GEMM (verified) ----------------
template<bool BTRANS, bool MASKED, bool RESID, int NGRP>
__global__ __launch_bounds__(256) void gemm_kernel(
    const float* __restrict__ A, const float* __restrict__ Bm, float* __restrict__ C,
    const float* __restrict__ resid, const int* __restrict__ mask,
    int K, int lda, int ldb, int ldc,
    long sA, long sB, long sC, long sR, long sM, float scale)
{
  constexpr int TM = 128, TK = 32, TN = 64*NGRP;
  __shared__ float As[TK][TM+4];
  __shared__ float Bs[TK][TN+4];
  const int z = blockIdx.z;
  A += z*sA; Bm += z*sB; C += z*sC;
  const float* rp = nullptr; const int* mp = nullptr;
  if constexpr (RESID)  rp = resid + z*sR;
  if constexpr (MASKED) mp = mask  + z*sM;
  const int m0 = blockIdx.x*TM, n0 = blockIdx.y*TN;
  const int tid = threadIdx.x, tx = tid & 15, ty = tid >> 4;
  float acc[2][NGRP][4][4] = {};

  for (int k0 = 0; k0 < K; k0 += TK) {
    #pragma unroll
    for (int e = tid; e < TM*TK/4; e += 256) {
      int m = e >> 3, k4 = (e & 7) << 2;
      float4 a = *(const float4*)&A[(long)(m0+m)*lda + k0 + k4];
      As[k4+0][m] = a.x; As[k4+1][m] = a.y; As[k4+2][m] = a.z; As[k4+3][m] = a.w;
    }
    if constexpr (BTRANS) {
      #pragma unroll
      for (int e = tid; e < TN*TK/4; e += 256) {
        int n = e >> 3, k4 = (e & 7) << 2;
        float4 b = *(const float4*)&Bm[(long)(n0+n)*ldb + k0 + k4];
        Bs[k4+0][n] = b.x; Bs[k4+1][n] = b.y; Bs[k4+2][n] = b.z; Bs[k4+3][n] = b.w;
      }
    } else {
      constexpr int TN4 = TN/4;
      #pragma unroll
      for (int e = tid; e < TK*TN4; e += 256) {
        int kk = e / TN4, n4 = (e % TN4) << 2;
        *(float4*)&Bs[kk][n4] = *(const float4*)&Bm[(long)(k0+kk)*ldb + n0 + n4];
      }
    }
    __syncthreads();
    #pragma unroll
    for (int kk = 0; kk < TK; kk++) {
      float av[2][4];
      float bv[NGRP][4];
      *(float4*)av[0] = *(const float4*)&As[kk][ty*4];
      *(float4*)av[1] = *(const float4*)&As[kk][64 + ty*4];
      #pragma unroll
      for (int g = 0; g < NGRP; g++)
        *(float4*)bv[g] = *(const float4*)&Bs[kk][g*64 + tx*4];
      #pragma unroll
      for (int mg = 0; mg < 2; mg++)
        #pragma unroll
        for (int r = 0; r < 4; r++)
          #pragma unroll
          for (int g = 0; g < NGRP; g++)
            #pragma unroll
            for (int c = 0; c < 4; c++)
              acc[mg][g][r][c] = fmaf(av[mg][r], bv[g][c], acc[mg][g][r][c]);
    }
    __syncthreads();
  }

  #pragma unroll
  for (int mg = 0; mg < 2; mg++) {
    #pragma unroll
    for (int r = 0; r < 4; r++) {
      const int m = m0 + mg*64 + ty*4 + r;
      #pragma unroll
      for (int g = 0; g < NGRP; g++) {
        const int n = n0 + g*64 + tx*4;
        float4 v;
        v.x = acc[mg][g][r][0]*scale; v.y = acc[mg][g][r][1]*scale;
        v.z = acc[mg][g][r][2]*scale; v.w = acc[mg][g][r][3]*scale;
        if constexpr (RESID) {
          float4 rv = *(const float4*)&rp[(long)m*ldc + n];
          v.x += rv.x; v.y += rv.y; v.z += rv.z; v.w += rv.w;
        }
        if constexpr (MASKED) {
          int4 mv = *(const int4*)&mp[(long)m*ldc + n];
          if (!mv.x) v.x = -1e9f;
          if (!mv.y) v.y = -1e9f;
          if (!mv.z) v.z = -1e9f;
          if (!mv.w) v.w = -1e9f;
        }
        *(float4*)&C[(long)m*ldc + n] = v;
      }
    }
  }
}

// ---------------- softmax in place (GAMMA=1) ----------------
__global__ __launch_bounds__(256) void softmax_kernel(float* __restrict__ attn)
{
  const long row = blockIdx.x;
  float* p = attn + row*SEQ;
  const int t = threadIdx.x;
  float4 a = ((const float4*)p)[t];
  float4 b = ((const float4*)p)[t + 256];
  float f[8] = {a.x,a.y,a.z,a.w,b.x,b.y,b.z,b.w};
  float M = f[0];
  #pragma unroll
  for (int i = 1; i < 8; i++) M = fmaxf(M, f[i]);
  #pragma unroll
  for (int o = 1; o < 64; o <<= 1) M = fmaxf(M, __shfl_xor(M, o));
  __shared__ float r1[4], r2[4];
  if ((t & 63) == 0) r1[t >> 6] = M;
  __syncthreads();
  M = fmaxf(fmaxf(r1[0], r1[1]), fmaxf(r1[2], r1[3]));
  float s = 0.f;
  #pragma unroll
  for (int i = 0; i < 8; i++) { f[i] = __expf(f[i] - M); s += f[i]; }
  #pragma unroll
  for (int o = 1; o < 64; o <<= 1) s += __shfl_xor(s, o);
  if ((t & 63) == 0) r2[t >> 6] = s;
  __syncthreads();
  s = (r2[0] + r2[1]) + (r2[2] + r2[3]);
  const float inv = 1.0f / s;
  a.x = f[0]*inv; a.y = f[1]*inv; a.z = f[2]*inv; a.w = f[3]*inv;
  b.x = f[4]*inv; b.y = f[5]*inv; b.z = f[6]*inv; b.w = f[7]*inv;
  ((float4*)p)[t] = a;
  ((float4*)p)[t + 256] = b;
}

// ---------------- fused fc + LayerNorm in place (verified) ----------------
__global__ __launch_bounds__(256) void fc_ln_kernel(
    float* __restrict__ X, const float* __restrict__ W,
    const float* __restrict__ g, const float* __restrict__ b)
{
  __shared__ float As[32][32+4];
  __shared__ float Bs[32][512+4];
  const int tid = threadIdx.x;
  const long r0 = (long)blockIdx.x * 32;
  const int tx = tid & 63, ty = tid >> 6;
  float acc[8][8] = {};

  for (int k0 = 0; k0 < DIM; k0 += 32) {
    {
      int m = tid >> 3, k4 = (tid & 7) << 2;
      float4 a = *(const float4*)&X[(r0+m)*DIM + k0 + k4];
      As[k4+0][m] = a.x; As[k4+1][m] = a.y; As[k4+2][m] = a.z; As[k4+3][m] = a.w;
    }
    #pragma unroll
    for (int e = tid; e < 32*128; e += 256) {
      int kk = e >> 7, n4 = (e & 127) << 2;
      *(float4*)&Bs[kk][n4] = *(const float4*)&W[(long)(k0+kk)*DIM + n4];
    }
    __syncthreads();
    #pragma unroll
    for (int kk = 0; kk < 32; kk++) {
      float a[8], bb[8];
      *(float4*)&a[0]  = *(const float4*)&As[kk][ty*8];
      *(float4*)&a[4]  = *(const float4*)&As[kk][ty*8+4];
      *(float4*)&bb[0] = *(const float4*)&Bs[kk][tx*8];
      *(float4*)&bb[4] = *(const float4*)&Bs[kk][tx*8+4];
      #pragma unroll
      for (int r = 0; r < 8; r++)
        #pragma unroll
        for (int c = 0; c < 8; c++)
          acc[r][c] = fmaf(a[r], bb[c], acc[r][c]);
    }
    __syncthreads();
  }

  float gv[8], bv[8];
  *(float4*)&gv[0] = *(const float4*)&g[tx*8];
  *(float4*)&gv[4] = *(const float4*)&g[tx*8+4];
  *(float4*)&bv[0] = *(const float4*)&b[tx*8];
  *(float4*)&bv[4] = *(const float4*)&b[tx*8+4];

  #pragma unroll
  for (int r = 0; r < 8; r++) {
    float s = 0.f, sq = 0.f;
    #pragma unroll
    for (int c = 0; c < 8; c++) { s += acc[r][c]; sq += acc[r][c]*acc[r][c]; }
    #pragma unroll
    for (int o = 1; o < 64; o <<= 1) { s += __shfl_xor(s, o); sq += __shfl_xor(sq, o); }
    const float mean = s * (1.0f/DIM);
    float var = sq * (1.0f/DIM) - mean*mean;
    var = fmaxf(var, 0.0f);
    const float rs = rsqrtf(var + 1e-6f);
    float o0[8];
    #pragma unroll
    for (int c = 0; c < 8; c++) o0[c] = (acc[r][c] - mean)*rs*gv[c] + bv[c];
    float* dst = &X[(r0 + ty*8 + r)*DIM + tx*8];
    *(float4*)&dst[0] = *(const float4*)&o0[0];
    *(float4*)&dst[4] = *(const float4*)&o0[4];
  }
}

// ---------------- v transpose: vT[b][n][k] = bf16(v[b][k][n]) ----------------
__global__ __launch_bounds__(256) void transpose_v_kernel(
    const float* __restrict__ v, unsigned short* __restrict__ vT)
{
  __shared__ float T[64][65];
  const int b = blockIdx.z;
  const int k0 = blockIdx.x*64, n0 = blockIdx.y*64;
  const float* vb = v + (long)b*SEQ*DIM;
  unsigned short* tb = vT + (long)b*DIM*SEQ;
  const int t = threadIdx.x;
  {
    int kk = t >> 2, nq = (t & 3)*16;
    const float4* src = (const float4*)&vb[(long)(k0+kk)*DIM + n0 + nq];
    #pragma unroll
    for (int j = 0; j < 4; j++) {
      float4 x = src[j];
      T[kk][nq+4*j+0] = x.x; T[kk][nq+4*j+1] = x.y;
      T[kk][nq+4*j+2] = x.z; T[kk][nq+4*j+3] = x.w;
    }
  }
  __syncthreads();
  {
    int n = t >> 2, kq = (t & 3)*16;
    unsigned int w[8];
    #pragma unroll
    for (int j = 0; j < 8; j++)
      w[j] = pack_bf2(T[kq+2*j][n], T[kq+2*j+1][n]);
    unsigned short* dst = &tb[(long)(n0+n)*SEQ + k0 + kq];
    *(uint4*)&dst[0] = *(uint4*)&w[0];
    *(uint4*)&dst[8] = *(uint4*)&w[4];
  }
}

// ---------------- pass 5 MFMA: out[b] = attn[b]@v[b] + v[b] ----------------
// 128x128 tile, BK=64, 4 waves (2x2), each wave 64x64 = 4x4 tiles of 16x16x32 bf16.
// A (attn f32) converted to bf16 in staging; B from pre-transposed vT (bf16, k-contig).
__global__ __launch_bounds__(256) void attn_v_mfma_kernel(
    const float* __restrict__ attn, const unsigned short* __restrict__ vT,
    const float* __restrict__ v, float* __restrict__ out)
{
  __shared__ unsigned short As[128][72];   // [m][k], row stride 144B (2-way frag reads)
  __shared__ unsigned short Bs[128][72];   // [n][k]
  const int b = blockIdx.z;
  const float* ap = attn + (long)b*SEQ*SEQ;
  const unsigned short* bp = vT + (long)b*DIM*SEQ;
  const float* vp = v + (long)b*SEQ*DIM;
  float* op = out + (long)b*SEQ*DIM;
  const int m0 = blockIdx.x*128, n0 = blockIdx.y*128;
  const int tid = threadIdx.x;
  const int lane = tid & 63, wid = tid >> 6;
  const int wr = wid >> 1, wc = wid & 1;
  const int q = lane >> 4, l16 = lane & 15;

  f32x4 acc[4][4] = {};

  for (int k0 = 0; k0 < SEQ; k0 += 64) {
    { // A stage: 128 rows x 64 k f32 -> bf16
      int r = tid >> 1, h = tid & 1;
      const float4* src = (const float4*)&ap[(long)(m0+r)*SEQ + k0 + h*32];
      unsigned int tmp[16];
      #pragma unroll
      for (int j = 0; j < 8; j++) {
        float4 x = src[j];
        tmp[2*j]   = pack_bf2(x.x, x.y);
        tmp[2*j+1] = pack_bf2(x.z, x.w);
      }
      #pragma unroll
      for (int j = 0; j < 4; j++)
        *(uint4*)&As[r][h*32 + 8*j] = ((const uint4*)tmp)[j];
    }
    { // B stage: 128 n-rows x 64 k bf16, straight copy
      int n = tid >> 1, h = tid & 1;
      const uint4* src = (const uint4*)&bp[(long)(n0+n)*SEQ + k0 + h*32];
      uint4 b0 = src[0], b1 = src[1], b2 = src[2], b3 = src[3];
      *(uint4*)&Bs[n][h*32 +  0] = b0;
      *(uint4*)&Bs[n][h*32 +  8] = b1;
      *(uint4*)&Bs[n][h*32 + 16] = b2;
      *(uint4*)&Bs[n][h*32 + 24] = b3;
    }
    __syncthreads();
    #pragma unroll
    for (int ks = 0; ks < 2; ks++) {
      short8 af[4], bf[4];
      #pragma unroll
      for (int mt = 0; mt < 4; mt++)
        af[mt] = *(const short8*)&As[wr*64 + mt*16 + l16][ks*32 + q*8];
      #pragma unroll
      for (int nt = 0; nt < 4; nt++)
        bf[nt] = *(const short8*)&Bs[wc*64 + nt*16 + l16][ks*32 + q*8];
      #pragma unroll
      for (int mt = 0; mt < 4; mt++)
        #pragma unroll
        for (int nt = 0; nt < 4; nt++)
          acc[mt][nt] = __builtin_amdgcn_mfma_f32_16x16x32_bf16(af[mt], bf[nt], acc[mt][nt], 0, 0, 0);
    }
    __syncthreads();
  }

  // epilogue: C/D layout col=lane&15, row=q*4+reg; add v residual (f32)
  #pragma unroll
  for (int mt = 0; mt < 4; mt++) {
    #pragma unroll
    for (int nt = 0; nt < 4; nt++) {
      const int col = n0 + wc*64 + nt*16 + l16;
      #pragma unroll
      for (int r = 0; r < 4; r++) {
        const int row = m0 + wr*64 + mt*16 + q*4 + r;
        op[(long)row*DIM + col] = acc[mt][nt][r] + vp[(long)row*DIM + col];
      }
    }
  }
}

extern "C" void kernel_launch(void* const* d_in, const int* in_sizes, int n_in,
                              void* d_out, int out_size, void* d_ws, size_t ws_size,
                              hipStream_t stream) {
  const float* q    = (const float*)d_in[0];
  const float* k    = (const float*)d_in[1];
  const float* v    = (const float*)d_in[2];
  const int*   mask = (const int*)d_in[3];
  const float* w_qs = (const float*)d_in[4];
  const float* w_ks = (const float*)d_in[5];
  const float* w_fc = (const float*)d_in[6];
  const float* ln_g = (const float*)d_in[7];
  const float* ln_b = (const float*)d_in[8];

  float* out   = (float*)d_out;                       // [B,N,DIM]
  float* attnF = out + (long)BB*SEQ*DIM;              // [B,N,N]: scores -> softmax in place

  float* qp = out;                                    // scratch inside out region (dead after pass 3)
  float* kp = out + (long)BB*SEQ*DK;

  const long NN2 = (long)SEQ*SEQ;
  const long ND  = (long)SEQ*DIM;
  const long NK  = (long)SEQ*DK;

  const size_t vT_bytes = (size_t)BB*DIM*SEQ*sizeof(unsigned short);  // 8.4 MB
  const bool fast = (ws_size >= vT_bytes);            // constant per process -> graph-safe

  // 1) qp = (q @ w_qs) / 8
  gemm_kernel<false,false,false,1><<<dim3(BB*SEQ/128,1,1), 256, 0, stream>>>(
      q, w_qs, qp, nullptr, nullptr, DIM, DIM, DK, DK, 0,0,0,0,0, 0.125f);
  // 2) kp = k @ w_ks
  gemm_kernel<false,false,false,1><<<dim3(BB*SEQ/128,1,1), 256, 0, stream>>>(
      k, w_ks, kp, nullptr, nullptr, DIM, DIM, DK, DK, 0,0,0,0,0, 1.0f);
  // 3) scores[b] = qp[b] @ kp[b]^T, mask==0 -> -1e9
  gemm_kernel<true,true,false,2><<<dim3(SEQ/128,SEQ/128,BB), 256, 0, stream>>>(
      qp, kp, attnF, nullptr, mask, DK, DK, DK, SEQ, NK, NK, NN2, 0, NN2, 1.0f);
  // 4) softmax in place
  softmax_kernel<<<dim3(BB*SEQ,1,1), 256, 0, stream>>>(attnF);
  // 5) out = attn @ v + v
  if (fast) {
    unsigned short* vT = (unsigned short*)d_ws;
    transpose_v_kernel<<<dim3(SEQ/64, DIM/64, BB), 256, 0, stream>>>(v, vT);
    attn_v_mfma_kernel<<<dim3(SEQ/128, DIM/128, BB), 256, 0, stream>>>(attnF, vT, v, out);
  } else {
    gemm_kernel<false,false,true,2><<<dim3(SEQ/128,DIM/128,BB), 256, 0, stream>>>(
        attnF, v, out, v, nullptr, SEQ, SEQ, DIM, DIM, NN2, ND, ND, ND, 0, 1.0f);
  }
  // 6+7) out = LayerNorm(out @ w_fc), fused, in place
  fc_ln_kernel<<<dim3(BB*SEQ/32,1,1), 256, 0, stream>>>(out, w_fc, ln_g, ln_b);
}

// Round 5
// 484.542 us; speedup vs baseline: 1.8167x; 1.2439x over previous
//
#include <hip/hip_runtime.h>
#include <hip/hip_bf16.h>

#define BB  4
#define SEQ 2048
#define DIM 512
#define DK  64

typedef __attribute__((ext_vector_type(8))) short short8;
typedef __attribute__((ext_vector_type(4))) float f32x4;

__device__ __forceinline__ unsigned int pack_bf2(float a, float b){
  __hip_bfloat16 ha = __float2bfloat16(a), hb = __float2bfloat16(b);
  unsigned short ua = __builtin_bit_cast(unsigned short, ha);
  unsigned short ub = __builtin_bit_cast(unsigned short, hb);
  return (unsigned int)ua | ((unsigned int)ub << 16);
}

// ---------------- Tiled f32 GEMM (verified) ----------------
template<bool BTRANS, bool MASKED, bool RESID, int NGRP>
__global__ __launch_bounds__(256) void gemm_kernel(
    const float* __restrict__ A, const float* __restrict__ Bm, float* __restrict__ C,
    const float* __restrict__ resid, const int* __restrict__ mask,
    int K, int lda, int ldb, int ldc,
    long sA, long sB, long sC, long sR, long sM, float scale)
{
  constexpr int TM = 128, TK = 32, TN = 64*NGRP;
  __shared__ float As[TK][TM+4];
  __shared__ float Bs[TK][TN+4];
  const int z = blockIdx.z;
  A += z*sA; Bm += z*sB; C += z*sC;
  const float* rp = nullptr; const int* mp = nullptr;
  if constexpr (RESID)  rp = resid + z*sR;
  if constexpr (MASKED) mp = mask  + z*sM;
  const int m0 = blockIdx.x*TM, n0 = blockIdx.y*TN;
  const int tid = threadIdx.x, tx = tid & 15, ty = tid >> 4;
  float acc[2][NGRP][4][4] = {};

  for (int k0 = 0; k0 < K; k0 += TK) {
    #pragma unroll
    for (int e = tid; e < TM*TK/4; e += 256) {
      int m = e >> 3, k4 = (e & 7) << 2;
      float4 a = *(const float4*)&A[(long)(m0+m)*lda + k0 + k4];
      As[k4+0][m] = a.x; As[k4+1][m] = a.y; As[k4+2][m] = a.z; As[k4+3][m] = a.w;
    }
    if constexpr (BTRANS) {
      #pragma unroll
      for (int e = tid; e < TN*TK/4; e += 256) {
        int n = e >> 3, k4 = (e & 7) << 2;
        float4 b = *(const float4*)&Bm[(long)(n0+n)*ldb + k0 + k4];
        Bs[k4+0][n] = b.x; Bs[k4+1][n] = b.y; Bs[k4+2][n] = b.z; Bs[k4+3][n] = b.w;
      }
    } else {
      constexpr int TN4 = TN/4;
      #pragma unroll
      for (int e = tid; e < TK*TN4; e += 256) {
        int kk = e / TN4, n4 = (e % TN4) << 2;
        *(float4*)&Bs[kk][n4] = *(const float4*)&Bm[(long)(k0+kk)*ldb + n0 + n4];
      }
    }
    __syncthreads();
    #pragma unroll
    for (int kk = 0; kk < TK; kk++) {
      float av[2][4];
      float bv[NGRP][4];
      *(float4*)av[0] = *(const float4*)&As[kk][ty*4];
      *(float4*)av[1] = *(const float4*)&As[kk][64 + ty*4];
      #pragma unroll
      for (int g = 0; g < NGRP; g++)
        *(float4*)bv[g] = *(const float4*)&Bs[kk][g*64 + tx*4];
      #pragma unroll
      for (int mg = 0; mg < 2; mg++)
        #pragma unroll
        for (int r = 0; r < 4; r++)
          #pragma unroll
          for (int g = 0; g < NGRP; g++)
            #pragma unroll
            for (int c = 0; c < 4; c++)
              acc[mg][g][r][c] = fmaf(av[mg][r], bv[g][c], acc[mg][g][r][c]);
    }
    __syncthreads();
  }

  #pragma unroll
  for (int mg = 0; mg < 2; mg++) {
    #pragma unroll
    for (int r = 0; r < 4; r++) {
      const int m = m0 + mg*64 + ty*4 + r;
      #pragma unroll
      for (int g = 0; g < NGRP; g++) {
        const int n = n0 + g*64 + tx*4;
        float4 v;
        v.x = acc[mg][g][r][0]*scale; v.y = acc[mg][g][r][1]*scale;
        v.z = acc[mg][g][r][2]*scale; v.w = acc[mg][g][r][3]*scale;
        if constexpr (RESID) {
          float4 rv = *(const float4*)&rp[(long)m*ldc + n];
          v.x += rv.x; v.y += rv.y; v.z += rv.z; v.w += rv.w;
        }
        if constexpr (MASKED) {
          int4 mv = *(const int4*)&mp[(long)m*ldc + n];
          if (!mv.x) v.x = -1e9f;
          if (!mv.y) v.y = -1e9f;
          if (!mv.z) v.z = -1e9f;
          if (!mv.w) v.w = -1e9f;
        }
        *(float4*)&C[(long)m*ldc + n] = v;
      }
    }
  }
}

// ---------------- softmax in place (GAMMA=1) ----------------
__global__ __launch_bounds__(256) void softmax_kernel(float* __restrict__ attn)
{
  const long row = blockIdx.x;
  float* p = attn + row*SEQ;
  const int t = threadIdx.x;
  float4 a = ((const float4*)p)[t];
  float4 b = ((const float4*)p)[t + 256];
  float f[8] = {a.x,a.y,a.z,a.w,b.x,b.y,b.z,b.w};
  float M = f[0];
  #pragma unroll
  for (int i = 1; i < 8; i++) M = fmaxf(M, f[i]);
  #pragma unroll
  for (int o = 1; o < 64; o <<= 1) M = fmaxf(M, __shfl_xor(M, o));
  __shared__ float r1[4], r2[4];
  if ((t & 63) == 0) r1[t >> 6] = M;
  __syncthreads();
  M = fmaxf(fmaxf(r1[0], r1[1]), fmaxf(r1[2], r1[3]));
  float s = 0.f;
  #pragma unroll
  for (int i = 0; i < 8; i++) { f[i] = __expf(f[i] - M); s += f[i]; }
  #pragma unroll
  for (int o = 1; o < 64; o <<= 1) s += __shfl_xor(s, o);
  if ((t & 63) == 0) r2[t >> 6] = s;
  __syncthreads();
  s = (r2[0] + r2[1]) + (r2[2] + r2[3]);
  const float inv = 1.0f / s;
  a.x = f[0]*inv; a.y = f[1]*inv; a.z = f[2]*inv; a.w = f[3]*inv;
  b.x = f[4]*inv; b.y = f[5]*inv; b.z = f[6]*inv; b.w = f[7]*inv;
  ((float4*)p)[t] = a;
  ((float4*)p)[t + 256] = b;
}

// ---------------- fused fc + LayerNorm in place (VALU fallback, verified) ----------------
__global__ __launch_bounds__(256) void fc_ln_kernel(
    float* __restrict__ X, const float* __restrict__ W,
    const float* __restrict__ g, const float* __restrict__ b)
{
  __shared__ float As[32][32+4];
  __shared__ float Bs[32][512+4];
  const int tid = threadIdx.x;
  const long r0 = (long)blockIdx.x * 32;
  const int tx = tid & 63, ty = tid >> 6;
  float acc[8][8] = {};

  for (int k0 = 0; k0 < DIM; k0 += 32) {
    {
      int m = tid >> 3, k4 = (tid & 7) << 2;
      float4 a = *(const float4*)&X[(r0+m)*DIM + k0 + k4];
      As[k4+0][m] = a.x; As[k4+1][m] = a.y; As[k4+2][m] = a.z; As[k4+3][m] = a.w;
    }
    #pragma unroll
    for (int e = tid; e < 32*128; e += 256) {
      int kk = e >> 7, n4 = (e & 127) << 2;
      *(float4*)&Bs[kk][n4] = *(const float4*)&W[(long)(k0+kk)*DIM + n4];
    }
    __syncthreads();
    #pragma unroll
    for (int kk = 0; kk < 32; kk++) {
      float a[8], bb[8];
      *(float4*)&a[0]  = *(const float4*)&As[kk][ty*8];
      *(float4*)&a[4]  = *(const float4*)&As[kk][ty*8+4];
      *(float4*)&bb[0] = *(const float4*)&Bs[kk][tx*8];
      *(float4*)&bb[4] = *(const float4*)&Bs[kk][tx*8+4];
      #pragma unroll
      for (int r = 0; r < 8; r++)
        #pragma unroll
        for (int c = 0; c < 8; c++)
          acc[r][c] = fmaf(a[r], bb[c], acc[r][c]);
    }
    __syncthreads();
  }

  float gv[8], bv[8];
  *(float4*)&gv[0] = *(const float4*)&g[tx*8];
  *(float4*)&gv[4] = *(const float4*)&g[tx*8+4];
  *(float4*)&bv[0] = *(const float4*)&b[tx*8];
  *(float4*)&bv[4] = *(const float4*)&b[tx*8+4];

  #pragma unroll
  for (int r = 0; r < 8; r++) {
    float s = 0.f, sq = 0.f;
    #pragma unroll
    for (int c = 0; c < 8; c++) { s += acc[r][c]; sq += acc[r][c]*acc[r][c]; }
    #pragma unroll
    for (int o = 1; o < 64; o <<= 1) { s += __shfl_xor(s, o); sq += __shfl_xor(sq, o); }
    const float mean = s * (1.0f/DIM);
    float var = sq * (1.0f/DIM) - mean*mean;
    var = fmaxf(var, 0.0f);
    const float rs = rsqrtf(var + 1e-6f);
    float o0[8];
    #pragma unroll
    for (int c = 0; c < 8; c++) o0[c] = (acc[r][c] - mean)*rs*gv[c] + bv[c];
    float* dst = &X[(r0 + ty*8 + r)*DIM + tx*8];
    *(float4*)&dst[0] = *(const float4*)&o0[0];
    *(float4*)&dst[4] = *(const float4*)&o0[4];
  }
}

// ---------------- v transpose: vT[b][n][k] = bf16(v[b][k][n]) ----------------
__global__ __launch_bounds__(256) void transpose_v_kernel(
    const float* __restrict__ v, unsigned short* __restrict__ vT)
{
  __shared__ float T[64][65];
  const int b = blockIdx.z;
  const int k0 = blockIdx.x*64, n0 = blockIdx.y*64;
  const float* vb = v + (long)b*SEQ*DIM;
  unsigned short* tb = vT + (long)b*DIM*SEQ;
  const int t = threadIdx.x;
  {
    int kk = t >> 2, nq = (t & 3)*16;
    const float4* src = (const float4*)&vb[(long)(k0+kk)*DIM + n0 + nq];
    #pragma unroll
    for (int j = 0; j < 4; j++) {
      float4 x = src[j];
      T[kk][nq+4*j+0] = x.x; T[kk][nq+4*j+1] = x.y;
      T[kk][nq+4*j+2] = x.z; T[kk][nq+4*j+3] = x.w;
    }
  }
  __syncthreads();
  {
    int n = t >> 2, kq = (t & 3)*16;
    unsigned int w[8];
    #pragma unroll
    for (int j = 0; j < 8; j++)
      w[j] = pack_bf2(T[kq+2*j][n], T[kq+2*j+1][n]);
    unsigned short* dst = &tb[(long)(n0+n)*SEQ + k0 + kq];
    *(uint4*)&dst[0] = *(uint4*)&w[0];
    *(uint4*)&dst[8] = *(uint4*)&w[4];
  }
}

// ---------------- w_fc transpose: wT[n][k] = bf16(w_fc[k][n]), 512x512 ----------------
__global__ __launch_bounds__(256) void transpose_w_kernel(
    const float* __restrict__ w, unsigned short* __restrict__ wT)
{
  __shared__ float T[64][65];
  const int k0 = blockIdx.x*64, n0 = blockIdx.y*64;
  const int t = threadIdx.x;
  {
    int kk = t >> 2, nq = (t & 3)*16;
    const float4* src = (const float4*)&w[(long)(k0+kk)*DIM + n0 + nq];
    #pragma unroll
    for (int j = 0; j < 4; j++) {
      float4 x = src[j];
      T[kk][nq+4*j+0] = x.x; T[kk][nq+4*j+1] = x.y;
      T[kk][nq+4*j+2] = x.z; T[kk][nq+4*j+3] = x.w;
    }
  }
  __syncthreads();
  {
    int n = t >> 2, kq = (t & 3)*16;
    unsigned int wv[8];
    #pragma unroll
    for (int j = 0; j < 8; j++)
      wv[j] = pack_bf2(T[kq+2*j][n], T[kq+2*j+1][n]);
    unsigned short* dst = &wT[(long)(n0+n)*DIM + k0 + kq];
    *(uint4*)&dst[0] = *(uint4*)&wv[0];
    *(uint4*)&dst[8] = *(uint4*)&wv[4];
  }
}

// ---------------- pass 5 MFMA: out[b] = attn[b]@v[b] + v[b] (verified) ----------------
__global__ __launch_bounds__(256) void attn_v_mfma_kernel(
    const float* __restrict__ attn, const unsigned short* __restrict__ vT,
    const float* __restrict__ v, float* __restrict__ out)
{
  __shared__ unsigned short As[128][72];
  __shared__ unsigned short Bs[128][72];
  const int b = blockIdx.z;
  const float* ap = attn + (long)b*SEQ*SEQ;
  const unsigned short* bp = vT + (long)b*DIM*SEQ;
  const float* vp = v + (long)b*SEQ*DIM;
  float* op = out + (long)b*SEQ*DIM;
  const int m0 = blockIdx.x*128, n0 = blockIdx.y*128;
  const int tid = threadIdx.x;
  const int lane = tid & 63, wid = tid >> 6;
  const int wr = wid >> 1, wc = wid & 1;
  const int q = lane >> 4, l16 = lane & 15;

  f32x4 acc[4][4] = {};

  for (int k0 = 0; k0 < SEQ; k0 += 64) {
    {
      int r = tid >> 1, h = tid & 1;
      const float4* src = (const float4*)&ap[(long)(m0+r)*SEQ + k0 + h*32];
      unsigned int tmp[16];
      #pragma unroll
      for (int j = 0; j < 8; j++) {
        float4 x = src[j];
        tmp[2*j]   = pack_bf2(x.x, x.y);
        tmp[2*j+1] = pack_bf2(x.z, x.w);
      }
      #pragma unroll
      for (int j = 0; j < 4; j++)
        *(uint4*)&As[r][h*32 + 8*j] = ((const uint4*)tmp)[j];
    }
    {
      int n = tid >> 1, h = tid & 1;
      const uint4* src = (const uint4*)&bp[(long)(n0+n)*SEQ + k0 + h*32];
      uint4 b0 = src[0], b1 = src[1], b2 = src[2], b3 = src[3];
      *(uint4*)&Bs[n][h*32 +  0] = b0;
      *(uint4*)&Bs[n][h*32 +  8] = b1;
      *(uint4*)&Bs[n][h*32 + 16] = b2;
      *(uint4*)&Bs[n][h*32 + 24] = b3;
    }
    __syncthreads();
    #pragma unroll
    for (int ks = 0; ks < 2; ks++) {
      short8 af[4], bf[4];
      #pragma unroll
      for (int mt = 0; mt < 4; mt++)
        af[mt] = *(const short8*)&As[wr*64 + mt*16 + l16][ks*32 + q*8];
      #pragma unroll
      for (int nt = 0; nt < 4; nt++)
        bf[nt] = *(const short8*)&Bs[wc*64 + nt*16 + l16][ks*32 + q*8];
      #pragma unroll
      for (int mt = 0; mt < 4; mt++)
        #pragma unroll
        for (int nt = 0; nt < 4; nt++)
          acc[mt][nt] = __builtin_amdgcn_mfma_f32_16x16x32_bf16(af[mt], bf[nt], acc[mt][nt], 0, 0, 0);
    }
    __syncthreads();
  }

  #pragma unroll
  for (int mt = 0; mt < 4; mt++) {
    #pragma unroll
    for (int nt = 0; nt < 4; nt++) {
      const int col = n0 + wc*64 + nt*16 + l16;
      #pragma unroll
      for (int r = 0; r < 4; r++) {
        const int row = m0 + wr*64 + mt*16 + q*4 + r;
        op[(long)row*DIM + col] = acc[mt][nt][r] + vp[(long)row*DIM + col];
      }
    }
  }
}

// ---------------- fused fc + LN, MFMA, in place on X[8192,512] ----------------
// Block = 32 rows x all 512 cols (LN block-local). 4 waves: each owns 128 cols,
// 2x8 tiles of 16x16x32 bf16. BK=64, K=512. B from pre-transposed bf16 wT[n][k].
__global__ __launch_bounds__(256) void fc_ln_mfma_kernel(
    float* __restrict__ X, const unsigned short* __restrict__ wT,
    const float* __restrict__ g, const float* __restrict__ b)
{
  __shared__ unsigned short As[32][72];
  __shared__ unsigned short Bs[512][72];
  __shared__ float red_s[4][32], red_q[4][32];
  __shared__ float gs[512], bs[512];
  const int tid = threadIdx.x;
  const long r0 = (long)blockIdx.x * 32;
  const int lane = tid & 63, wid = tid >> 6;
  const int q = lane >> 4, l16 = lane & 15;

  gs[tid] = g[tid]; gs[tid+256] = g[tid+256];
  bs[tid] = b[tid]; bs[tid+256] = b[tid+256];

  f32x4 acc[2][8] = {};

  for (int k0 = 0; k0 < DIM; k0 += 64) {
    { // A: 32 rows x 64 k, f32 -> bf16. 256 threads x 8 floats.
      int r = tid >> 3, h = tid & 7;
      const float* src = &X[(r0+r)*DIM + k0 + h*8];
      float4 x0 = *(const float4*)src, x1 = *(const float4*)(src+4);
      unsigned int tmp[4] = {pack_bf2(x0.x,x0.y), pack_bf2(x0.z,x0.w),
                             pack_bf2(x1.x,x1.y), pack_bf2(x1.z,x1.w)};
      *(uint4*)&As[r][h*8] = *(uint4*)tmp;
    }
    // B: 512 n-rows x 64 k bf16 = 4096 uint4, 16 per thread.
    #pragma unroll
    for (int e = tid; e < 4096; e += 256) {
      int n = e >> 3, j = e & 7;
      *(uint4*)&Bs[n][j*8] = *(const uint4*)&wT[(long)n*DIM + k0 + j*8];
    }
    __syncthreads();
    #pragma unroll
    for (int ks = 0; ks < 2; ks++) {
      short8 af[2], bf[8];
      #pragma unroll
      for (int mt = 0; mt < 2; mt++)
        af[mt] = *(const short8*)&As[mt*16 + l16][ks*32 + q*8];
      #pragma unroll
      for (int nt = 0; nt < 8; nt++)
        bf[nt] = *(const short8*)&Bs[wid*128 + nt*16 + l16][ks*32 + q*8];
      #pragma unroll
      for (int mt = 0; mt < 2; mt++)
        #pragma unroll
        for (int nt = 0; nt < 8; nt++)
          acc[mt][nt] = __builtin_amdgcn_mfma_f32_16x16x32_bf16(af[mt], bf[nt], acc[mt][nt], 0, 0, 0);
    }
    __syncthreads();
  }

  // Per-row LN partials over this wave's 128 cols; butterfly within l16 group.
  #pragma unroll
  for (int mt = 0; mt < 2; mt++) {
    #pragma unroll
    for (int r = 0; r < 4; r++) {
      float s = 0.f, z = 0.f;
      #pragma unroll
      for (int nt = 0; nt < 8; nt++) { float v = acc[mt][nt][r]; s += v; z += v*v; }
      #pragma unroll
      for (int o = 1; o < 16; o <<= 1) { s += __shfl_xor(s, o); z += __shfl_xor(z, o); }
      if (l16 == 0) { red_s[wid][mt*16 + q*4 + r] = s; red_q[wid][mt*16 + q*4 + r] = z; }
    }
  }
  __syncthreads();

  float mean[2][4], rstd[2][4];
  #pragma unroll
  for (int mt = 0; mt < 2; mt++)
    #pragma unroll
    for (int r = 0; r < 4; r++) {
      const int row = mt*16 + q*4 + r;
      float s = (red_s[0][row] + red_s[1][row]) + (red_s[2][row] + red_s[3][row]);
      float z = (red_q[0][row] + red_q[1][row]) + (red_q[2][row] + red_q[3][row]);
      float mu = s * (1.0f/DIM);
      float var = z * (1.0f/DIM) - mu*mu;
      var = fmaxf(var, 0.0f);
      mean[mt][r] = mu;
      rstd[mt][r] = rsqrtf(var + 1e-6f);
    }

  #pragma unroll
  for (int mt = 0; mt < 2; mt++) {
    #pragma unroll
    for (int nt = 0; nt < 8; nt++) {
      const int col = wid*128 + nt*16 + l16;
      const float gg = gs[col], bb = bs[col];
      #pragma unroll
      for (int r = 0; r < 4; r++) {
        const long row = r0 + mt*16 + q*4 + r;
        X[row*DIM + col] = (acc[mt][nt][r] - mean[mt][r])*rstd[mt][r]*gg + bb;
      }
    }
  }
}

extern "C" void kernel_launch(void* const* d_in, const int* in_sizes, int n_in,
                              void* d_out, int out_size, void* d_ws, size_t ws_size,
                              hipStream_t stream) {
  const float* q    = (const float*)d_in[0];
  const float* k    = (const float*)d_in[1];
  const float* v    = (const float*)d_in[2];
  const int*   mask = (const int*)d_in[3];
  const float* w_qs = (const float*)d_in[4];
  const float* w_ks = (const float*)d_in[5];
  const float* w_fc = (const float*)d_in[6];
  const float* ln_g = (const float*)d_in[7];
  const float* ln_b = (const float*)d_in[8];

  float* out   = (float*)d_out;                       // [B,N,DIM]
  float* attnF = out + (long)BB*SEQ*DIM;              // [B,N,N]: scores -> softmax in place

  float* qp = out;                                    // scratch inside out region (dead after pass 3)
  float* kp = out + (long)BB*SEQ*DK;

  const long NN2 = (long)SEQ*SEQ;
  const long ND  = (long)SEQ*DIM;
  const long NK  = (long)SEQ*DK;

  const size_t vT_bytes = (size_t)BB*DIM*SEQ*sizeof(unsigned short);   // 8.4 MB
  const size_t wT_bytes = (size_t)DIM*DIM*sizeof(unsigned short);      // 0.5 MB
  const bool fast  = (ws_size >= vT_bytes);                 // constant -> graph-safe
  const bool fast2 = (ws_size >= vT_bytes + wT_bytes);

  // 1) qp = (q @ w_qs) / 8
  gemm_kernel<false,false,false,1><<<dim3(BB*SEQ/128,1,1), 256, 0, stream>>>(
      q, w_qs, qp, nullptr, nullptr, DIM, DIM, DK, DK, 0,0,0,0,0, 0.125f);
  // 2) kp = k @ w_ks
  gemm_kernel<false,false,false,1><<<dim3(BB*SEQ/128,1,1), 256, 0, stream>>>(
      k, w_ks, kp, nullptr, nullptr, DIM, DIM, DK, DK, 0,0,0,0,0, 1.0f);
  // 3) scores[b] = qp[b] @ kp[b]^T, mask==0 -> -1e9
  gemm_kernel<true,true,false,2><<<dim3(SEQ/128,SEQ/128,BB), 256, 0, stream>>>(
      qp, kp, attnF, nullptr, mask, DK, DK, DK, SEQ, NK, NK, NN2, 0, NN2, 1.0f);
  // 4) softmax in place
  softmax_kernel<<<dim3(BB*SEQ,1,1), 256, 0, stream>>>(attnF);
  // 5) out = attn @ v + v
  if (fast) {
    unsigned short* vT = (unsigned short*)d_ws;
    transpose_v_kernel<<<dim3(SEQ/64, DIM/64, BB), 256, 0, stream>>>(v, vT);
    attn_v_mfma_kernel<<<dim3(SEQ/128, DIM/128, BB), 256, 0, stream>>>(attnF, vT, v, out);
  } else {
    gemm_kernel<false,false,true,2><<<dim3(SEQ/128,DIM/128,BB), 256, 0, stream>>>(
        attnF, v, out, v, nullptr, SEQ, SEQ, DIM, DIM, NN2, ND, ND, ND, 0, 1.0f);
  }
  // 6+7) out = LayerNorm(out @ w_fc), fused, in place
  if (fast2) {
    unsigned short* wT = (unsigned short*)d_ws + (size_t)BB*DIM*SEQ;
    transpose_w_kernel<<<dim3(DIM/64, DIM/64, 1), 256, 0, stream>>>(w_fc, wT);
    fc_ln_mfma_kernel<<<dim3(BB*SEQ/32,1,1), 256, 0, stream>>>(out, wT, ln_g, ln_b);
  } else {
    fc_ln_kernel<<<dim3(BB*SEQ/32,1,1), 256, 0, stream>>>(out, w_fc, ln_g, ln_b);
  }
}

// Round 6
// 348.394 us; speedup vs baseline: 2.5267x; 1.3908x over previous
//
#include <hip/hip_runtime.h>
#include <hip/hip_bf16.h>

#define BB  4
#define SEQ 2048
#define DIM 512
#define DK  64

typedef __attribute__((ext_vector_type(8))) short short8;
typedef __attribute__((ext_vector_type(4))) float f32x4;

__device__ __forceinline__ unsigned int pack_bf2(float a, float b){
  __hip_bfloat16 ha = __float2bfloat16(a), hb = __float2bfloat16(b);
  unsigned short ua = __builtin_bit_cast(unsigned short, ha);
  unsigned short ub = __builtin_bit_cast(unsigned short, hb);
  return (unsigned int)ua | ((unsigned int)ub << 16);
}
__device__ __forceinline__ unsigned short to_bf(float a){
  return __builtin_bit_cast(unsigned short, __float2bfloat16(a));
}

// ---------------- Tiled f32 GEMM (verified; kept for attn_v fallback) ----------------
template<bool BTRANS, bool MASKED, bool RESID, int NGRP>
__global__ __launch_bounds__(256) void gemm_kernel(
    const float* __restrict__ A, const float* __restrict__ Bm, float* __restrict__ C,
    const float* __restrict__ resid, const int* __restrict__ mask,
    int K, int lda, int ldb, int ldc,
    long sA, long sB, long sC, long sR, long sM, float scale)
{
  constexpr int TM = 128, TK = 32, TN = 64*NGRP;
  __shared__ float As[TK][TM+4];
  __shared__ float Bs[TK][TN+4];
  const int z = blockIdx.z;
  A += z*sA; Bm += z*sB; C += z*sC;
  const float* rp = nullptr; const int* mp = nullptr;
  if constexpr (RESID)  rp = resid + z*sR;
  if constexpr (MASKED) mp = mask  + z*sM;
  const int m0 = blockIdx.x*TM, n0 = blockIdx.y*TN;
  const int tid = threadIdx.x, tx = tid & 15, ty = tid >> 4;
  float acc[2][NGRP][4][4] = {};

  for (int k0 = 0; k0 < K; k0 += TK) {
    #pragma unroll
    for (int e = tid; e < TM*TK/4; e += 256) {
      int m = e >> 3, k4 = (e & 7) << 2;
      float4 a = *(const float4*)&A[(long)(m0+m)*lda + k0 + k4];
      As[k4+0][m] = a.x; As[k4+1][m] = a.y; As[k4+2][m] = a.z; As[k4+3][m] = a.w;
    }
    if constexpr (BTRANS) {
      #pragma unroll
      for (int e = tid; e < TN*TK/4; e += 256) {
        int n = e >> 3, k4 = (e & 7) << 2;
        float4 b = *(const float4*)&Bm[(long)(n0+n)*ldb + k0 + k4];
        Bs[k4+0][n] = b.x; Bs[k4+1][n] = b.y; Bs[k4+2][n] = b.z; Bs[k4+3][n] = b.w;
      }
    } else {
      constexpr int TN4 = TN/4;
      #pragma unroll
      for (int e = tid; e < TK*TN4; e += 256) {
        int kk = e / TN4, n4 = (e % TN4) << 2;
        *(float4*)&Bs[kk][n4] = *(const float4*)&Bm[(long)(k0+kk)*ldb + n0 + n4];
      }
    }
    __syncthreads();
    #pragma unroll
    for (int kk = 0; kk < TK; kk++) {
      float av[2][4];
      float bv[NGRP][4];
      *(float4*)av[0] = *(const float4*)&As[kk][ty*4];
      *(float4*)av[1] = *(const float4*)&As[kk][64 + ty*4];
      #pragma unroll
      for (int g = 0; g < NGRP; g++)
        *(float4*)bv[g] = *(const float4*)&Bs[kk][g*64 + tx*4];
      #pragma unroll
      for (int mg = 0; mg < 2; mg++)
        #pragma unroll
        for (int r = 0; r < 4; r++)
          #pragma unroll
          for (int g = 0; g < NGRP; g++)
            #pragma unroll
            for (int c = 0; c < 4; c++)
              acc[mg][g][r][c] = fmaf(av[mg][r], bv[g][c], acc[mg][g][r][c]);
    }
    __syncthreads();
  }

  #pragma unroll
  for (int mg = 0; mg < 2; mg++) {
    #pragma unroll
    for (int r = 0; r < 4; r++) {
      const int m = m0 + mg*64 + ty*4 + r;
      #pragma unroll
      for (int g = 0; g < NGRP; g++) {
        const int n = n0 + g*64 + tx*4;
        float4 v;
        v.x = acc[mg][g][r][0]*scale; v.y = acc[mg][g][r][1]*scale;
        v.z = acc[mg][g][r][2]*scale; v.w = acc[mg][g][r][3]*scale;
        if constexpr (RESID) {
          float4 rv = *(const float4*)&rp[(long)m*ldc + n];
          v.x += rv.x; v.y += rv.y; v.z += rv.z; v.w += rv.w;
        }
        if constexpr (MASKED) {
          int4 mv = *(const int4*)&mp[(long)m*ldc + n];
          if (!mv.x) v.x = -1e9f;
          if (!mv.y) v.y = -1e9f;
          if (!mv.z) v.z = -1e9f;
          if (!mv.w) v.w = -1e9f;
        }
        *(float4*)&C[(long)m*ldc + n] = v;
      }
    }
  }
}

// ---------------- fused q/k projection, MFMA, bf16 out ----------------
// grid (SEQ*BB/64, 2): y=0 -> qp=(q@w_qs)/8, y=1 -> kp=k@w_ks. Block: 64 rows x 64 cols,
// BK=64, 4 waves each own 16 rows x 64 cols (1 mt x 4 nt of 16x16x32).
__global__ __launch_bounds__(256) void proj_mfma_kernel(
    const float* __restrict__ q, const float* __restrict__ k,
    const float* __restrict__ w_qs, const float* __restrict__ w_ks,
    unsigned short* __restrict__ qp, unsigned short* __restrict__ kp)
{
  __shared__ unsigned short As[64][72];
  __shared__ unsigned short Bs[64][72];
  const int z = blockIdx.y;
  const float* A = z ? k : q;
  const float* W = z ? w_ks : w_qs;
  unsigned short* D = z ? kp : qp;
  const float scale = z ? 1.0f : 0.125f;
  const long m0 = (long)blockIdx.x * 64;
  const int tid = threadIdx.x;
  const int lane = tid & 63, wid = tid >> 6;
  const int qq = lane >> 4, l16 = lane & 15;
  f32x4 acc[4] = {};

  for (int k0 = 0; k0 < DIM; k0 += 64) {
    { // A: 64 rows x 64 k f32 -> bf16; thread: r=t>>2, 16 k each
      int r = tid >> 2, h = tid & 3;
      const float* src = &A[(m0+r)*DIM + k0 + h*16];
      float4 x0 = *(const float4*)src,     x1 = *(const float4*)(src+4),
             x2 = *(const float4*)(src+8), x3 = *(const float4*)(src+12);
      unsigned int tmp[8] = {pack_bf2(x0.x,x0.y),pack_bf2(x0.z,x0.w),
                             pack_bf2(x1.x,x1.y),pack_bf2(x1.z,x1.w),
                             pack_bf2(x2.x,x2.y),pack_bf2(x2.z,x2.w),
                             pack_bf2(x3.x,x3.y),pack_bf2(x3.z,x3.w)};
      *(uint4*)&As[r][h*16]   = ((uint4*)tmp)[0];
      *(uint4*)&As[r][h*16+8] = ((uint4*)tmp)[1];
    }
    { // B: W[k0+kk][n] f32 -> Bs[n][kk] bf16 (transpose in staging)
      int kk = tid >> 2, n4 = (tid & 3) * 16;
      const float* src = &W[(long)(k0+kk)*DK + n4];
      float4 y0 = *(const float4*)src,     y1 = *(const float4*)(src+4),
             y2 = *(const float4*)(src+8), y3 = *(const float4*)(src+12);
      float yv[16] = {y0.x,y0.y,y0.z,y0.w, y1.x,y1.y,y1.z,y1.w,
                      y2.x,y2.y,y2.z,y2.w, y3.x,y3.y,y3.z,y3.w};
      #pragma unroll
      for (int j = 0; j < 16; j++)
        Bs[n4+j][kk] = to_bf(yv[j]);
    }
    __syncthreads();
    #pragma unroll
    for (int ks = 0; ks < 2; ks++) {
      short8 af = *(const short8*)&As[wid*16 + l16][ks*32 + qq*8];
      #pragma unroll
      for (int nt = 0; nt < 4; nt++) {
        short8 bf = *(const short8*)&Bs[nt*16 + l16][ks*32 + qq*8];
        acc[nt] = __builtin_amdgcn_mfma_f32_16x16x32_bf16(af, bf, acc[nt], 0, 0, 0);
      }
    }
    __syncthreads();
  }

  #pragma unroll
  for (int nt = 0; nt < 4; nt++) {
    const int col = nt*16 + l16;
    #pragma unroll
    for (int r = 0; r < 4; r++) {
      const long row = m0 + wid*16 + qq*4 + r;
      D[row*DK + col] = to_bf(acc[nt][r] * scale);
    }
  }
}

// ---------------- scores MFMA: s[b] = qp[b]@kp[b]^T, mask==0 -> -1e9, f32 out ----------------
// 128x128 tile, K=64 (2 MFMA steps, no k-loop). qp/kp are bf16 [row][k] k-contig.
__global__ __launch_bounds__(256) void scores_mfma_kernel(
    const unsigned short* __restrict__ qp, const unsigned short* __restrict__ kp,
    const int* __restrict__ mask, float* __restrict__ scores)
{
  __shared__ unsigned short As[128][72];
  __shared__ unsigned short Bs[128][72];
  const int b = blockIdx.z;
  const unsigned short* ap = qp + (long)b*SEQ*DK;
  const unsigned short* bp = kp + (long)b*SEQ*DK;
  const int* mp = mask + (long)b*SEQ*SEQ;
  float* sp = scores + (long)b*SEQ*SEQ;
  const int m0 = blockIdx.x*128, n0 = blockIdx.y*128;
  const int tid = threadIdx.x;
  const int lane = tid & 63, wid = tid >> 6;
  const int wr = wid >> 1, wc = wid & 1;
  const int qq = lane >> 4, l16 = lane & 15;

  { // stage A,B: 128 rows x 64 k bf16 each, straight uint4 copies
    int r = tid >> 1, h = tid & 1;
    const uint4* srcA = (const uint4*)&ap[(long)(m0+r)*DK + h*32];
    const uint4* srcB = (const uint4*)&bp[(long)(n0+r)*DK + h*32];
    uint4 a0=srcA[0],a1=srcA[1],a2=srcA[2],a3=srcA[3];
    uint4 b0=srcB[0],b1=srcB[1],b2=srcB[2],b3=srcB[3];
    *(uint4*)&As[r][h*32+ 0]=a0; *(uint4*)&As[r][h*32+ 8]=a1;
    *(uint4*)&As[r][h*32+16]=a2; *(uint4*)&As[r][h*32+24]=a3;
    *(uint4*)&Bs[r][h*32+ 0]=b0; *(uint4*)&Bs[r][h*32+ 8]=b1;
    *(uint4*)&Bs[r][h*32+16]=b2; *(uint4*)&Bs[r][h*32+24]=b3;
  }
  __syncthreads();

  f32x4 acc[4][4] = {};
  #pragma unroll
  for (int ks = 0; ks < 2; ks++) {
    short8 af[4], bf[4];
    #pragma unroll
    for (int mt = 0; mt < 4; mt++)
      af[mt] = *(const short8*)&As[wr*64 + mt*16 + l16][ks*32 + qq*8];
    #pragma unroll
    for (int nt = 0; nt < 4; nt++)
      bf[nt] = *(const short8*)&Bs[wc*64 + nt*16 + l16][ks*32 + qq*8];
    #pragma unroll
    for (int mt = 0; mt < 4; mt++)
      #pragma unroll
      for (int nt = 0; nt < 4; nt++)
        acc[mt][nt] = __builtin_amdgcn_mfma_f32_16x16x32_bf16(af[mt], bf[nt], acc[mt][nt], 0, 0, 0);
  }

  #pragma unroll
  for (int mt = 0; mt < 4; mt++) {
    #pragma unroll
    for (int nt = 0; nt < 4; nt++) {
      const int col = n0 + wc*64 + nt*16 + l16;
      #pragma unroll
      for (int r = 0; r < 4; r++) {
        const long row = m0 + wr*64 + mt*16 + qq*4 + r;
        float vv = acc[mt][nt][r];
        if (mp[row*SEQ + col] == 0) vv = -1e9f;
        sp[row*SEQ + col] = vv;
      }
    }
  }
}

// ---------------- softmax in place (GAMMA=1, verified) ----------------
__global__ __launch_bounds__(256) void softmax_kernel(float* __restrict__ attn)
{
  const long row = blockIdx.x;
  float* p = attn + row*SEQ;
  const int t = threadIdx.x;
  float4 a = ((const float4*)p)[t];
  float4 b = ((const float4*)p)[t + 256];
  float f[8] = {a.x,a.y,a.z,a.w,b.x,b.y,b.z,b.w};
  float M = f[0];
  #pragma unroll
  for (int i = 1; i < 8; i++) M = fmaxf(M, f[i]);
  #pragma unroll
  for (int o = 1; o < 64; o <<= 1) M = fmaxf(M, __shfl_xor(M, o));
  __shared__ float r1[4], r2[4];
  if ((t & 63) == 0) r1[t >> 6] = M;
  __syncthreads();
  M = fmaxf(fmaxf(r1[0], r1[1]), fmaxf(r1[2], r1[3]));
  float s = 0.f;
  #pragma unroll
  for (int i = 0; i < 8; i++) { f[i] = __expf(f[i] - M); s += f[i]; }
  #pragma unroll
  for (int o = 1; o < 64; o <<= 1) s += __shfl_xor(s, o);
  if ((t & 63) == 0) r2[t >> 6] = s;
  __syncthreads();
  s = (r2[0] + r2[1]) + (r2[2] + r2[3]);
  const float inv = 1.0f / s;
  a.x = f[0]*inv; a.y = f[1]*inv; a.z = f[2]*inv; a.w = f[3]*inv;
  b.x = f[4]*inv; b.y = f[5]*inv; b.z = f[6]*inv; b.w = f[7]*inv;
  ((float4*)p)[t] = a;
  ((float4*)p)[t + 256] = b;
}

// ---------------- fused fc + LayerNorm in place (VALU fallback, verified) ----------------
__global__ __launch_bounds__(256) void fc_ln_kernel(
    float* __restrict__ X, const float* __restrict__ W,
    const float* __restrict__ g, const float* __restrict__ b)
{
  __shared__ float As[32][32+4];
  __shared__ float Bs[32][512+4];
  const int tid = threadIdx.x;
  const long r0 = (long)blockIdx.x * 32;
  const int tx = tid & 63, ty = tid >> 6;
  float acc[8][8] = {};

  for (int k0 = 0; k0 < DIM; k0 += 32) {
    {
      int m = tid >> 3, k4 = (tid & 7) << 2;
      float4 a = *(const float4*)&X[(r0+m)*DIM + k0 + k4];
      As[k4+0][m] = a.x; As[k4+1][m] = a.y; As[k4+2][m] = a.z; As[k4+3][m] = a.w;
    }
    #pragma unroll
    for (int e = tid; e < 32*128; e += 256) {
      int kk = e >> 7, n4 = (e & 127) << 2;
      *(float4*)&Bs[kk][n4] = *(const float4*)&W[(long)(k0+kk)*DIM + n4];
    }
    __syncthreads();
    #pragma unroll
    for (int kk = 0; kk < 32; kk++) {
      float a[8], bb[8];
      *(float4*)&a[0]  = *(const float4*)&As[kk][ty*8];
      *(float4*)&a[4]  = *(const float4*)&As[kk][ty*8+4];
      *(float4*)&bb[0] = *(const float4*)&Bs[kk][tx*8];
      *(float4*)&bb[4] = *(const float4*)&Bs[kk][tx*8+4];
      #pragma unroll
      for (int r = 0; r < 8; r++)
        #pragma unroll
        for (int c = 0; c < 8; c++)
          acc[r][c] = fmaf(a[r], bb[c], acc[r][c]);
    }
    __syncthreads();
  }

  float gv[8], bv[8];
  *(float4*)&gv[0] = *(const float4*)&g[tx*8];
  *(float4*)&gv[4] = *(const float4*)&g[tx*8+4];
  *(float4*)&bv[0] = *(const float4*)&b[tx*8];
  *(float4*)&bv[4] = *(const float4*)&b[tx*8+4];

  #pragma unroll
  for (int r = 0; r < 8; r++) {
    float s = 0.f, sq = 0.f;
    #pragma unroll
    for (int c = 0; c < 8; c++) { s += acc[r][c]; sq += acc[r][c]*acc[r][c]; }
    #pragma unroll
    for (int o = 1; o < 64; o <<= 1) { s += __shfl_xor(s, o); sq += __shfl_xor(sq, o); }
    const float mean = s * (1.0f/DIM);
    float var = sq * (1.0f/DIM) - mean*mean;
    var = fmaxf(var, 0.0f);
    const float rs = rsqrtf(var + 1e-6f);
    float o0[8];
    #pragma unroll
    for (int c = 0; c < 8; c++) o0[c] = (acc[r][c] - mean)*rs*gv[c] + bv[c];
    float* dst = &X[(r0 + ty*8 + r)*DIM + tx*8];
    *(float4*)&dst[0] = *(const float4*)&o0[0];
    *(float4*)&dst[4] = *(const float4*)&o0[4];
  }
}

// ---------------- v transpose: vT[b][n][k] = bf16(v[b][k][n]) ----------------
__global__ __launch_bounds__(256) void transpose_v_kernel(
    const float* __restrict__ v, unsigned short* __restrict__ vT)
{
  __shared__ float T[64][65];
  const int b = blockIdx.z;
  const int k0 = blockIdx.x*64, n0 = blockIdx.y*64;
  const float* vb = v + (long)b*SEQ*DIM;
  unsigned short* tb = vT + (long)b*DIM*SEQ;
  const int t = threadIdx.x;
  {
    int kk = t >> 2, nq = (t & 3)*16;
    const float4* src = (const float4*)&vb[(long)(k0+kk)*DIM + n0 + nq];
    #pragma unroll
    for (int j = 0; j < 4; j++) {
      float4 x = src[j];
      T[kk][nq+4*j+0] = x.x; T[kk][nq+4*j+1] = x.y;
      T[kk][nq+4*j+2] = x.z; T[kk][nq+4*j+3] = x.w;
    }
  }
  __syncthreads();
  {
    int n = t >> 2, kq = (t & 3)*16;
    unsigned int w[8];
    #pragma unroll
    for (int j = 0; j < 8; j++)
      w[j] = pack_bf2(T[kq+2*j][n], T[kq+2*j+1][n]);
    unsigned short* dst = &tb[(long)(n0+n)*SEQ + k0 + kq];
    *(uint4*)&dst[0] = *(uint4*)&w[0];
    *(uint4*)&dst[8] = *(uint4*)&w[4];
  }
}

// ---------------- w_fc transpose: wT[n][k] = bf16(w_fc[k][n]) ----------------
__global__ __launch_bounds__(256) void transpose_w_kernel(
    const float* __restrict__ w, unsigned short* __restrict__ wT)
{
  __shared__ float T[64][65];
  const int k0 = blockIdx.x*64, n0 = blockIdx.y*64;
  const int t = threadIdx.x;
  {
    int kk = t >> 2, nq = (t & 3)*16;
    const float4* src = (const float4*)&w[(long)(k0+kk)*DIM + n0 + nq];
    #pragma unroll
    for (int j = 0; j < 4; j++) {
      float4 x = src[j];
      T[kk][nq+4*j+0] = x.x; T[kk][nq+4*j+1] = x.y;
      T[kk][nq+4*j+2] = x.z; T[kk][nq+4*j+3] = x.w;
    }
  }
  __syncthreads();
  {
    int n = t >> 2, kq = (t & 3)*16;
    unsigned int wv[8];
    #pragma unroll
    for (int j = 0; j < 8; j++)
      wv[j] = pack_bf2(T[kq+2*j][n], T[kq+2*j+1][n]);
    unsigned short* dst = &wT[(long)(n0+n)*DIM + k0 + kq];
    *(uint4*)&dst[0] = *(uint4*)&wv[0];
    *(uint4*)&dst[8] = *(uint4*)&wv[4];
  }
}

// ---------------- pass 5 MFMA: out[b] = attn[b]@v[b] + v[b] (verified) ----------------
__global__ __launch_bounds__(256) void attn_v_mfma_kernel(
    const float* __restrict__ attn, const unsigned short* __restrict__ vT,
    const float* __restrict__ v, float* __restrict__ out)
{
  __shared__ unsigned short As[128][72];
  __shared__ unsigned short Bs[128][72];
  const int b = blockIdx.z;
  const float* ap = attn + (long)b*SEQ*SEQ;
  const unsigned short* bp = vT + (long)b*DIM*SEQ;
  const float* vp = v + (long)b*SEQ*DIM;
  float* op = out + (long)b*SEQ*DIM;
  const int m0 = blockIdx.x*128, n0 = blockIdx.y*128;
  const int tid = threadIdx.x;
  const int lane = tid & 63, wid = tid >> 6;
  const int wr = wid >> 1, wc = wid & 1;
  const int q = lane >> 4, l16 = lane & 15;

  f32x4 acc[4][4] = {};

  for (int k0 = 0; k0 < SEQ; k0 += 64) {
    {
      int r = tid >> 1, h = tid & 1;
      const float4* src = (const float4*)&ap[(long)(m0+r)*SEQ + k0 + h*32];
      unsigned int tmp[16];
      #pragma unroll
      for (int j = 0; j < 8; j++) {
        float4 x = src[j];
        tmp[2*j]   = pack_bf2(x.x, x.y);
        tmp[2*j+1] = pack_bf2(x.z, x.w);
      }
      #pragma unroll
      for (int j = 0; j < 4; j++)
        *(uint4*)&As[r][h*32 + 8*j] = ((const uint4*)tmp)[j];
    }
    {
      int n = tid >> 1, h = tid & 1;
      const uint4* src = (const uint4*)&bp[(long)(n0+n)*SEQ + k0 + h*32];
      uint4 b0 = src[0], b1 = src[1], b2 = src[2], b3 = src[3];
      *(uint4*)&Bs[n][h*32 +  0] = b0;
      *(uint4*)&Bs[n][h*32 +  8] = b1;
      *(uint4*)&Bs[n][h*32 + 16] = b2;
      *(uint4*)&Bs[n][h*32 + 24] = b3;
    }
    __syncthreads();
    #pragma unroll
    for (int ks = 0; ks < 2; ks++) {
      short8 af[4], bf[4];
      #pragma unroll
      for (int mt = 0; mt < 4; mt++)
        af[mt] = *(const short8*)&As[wr*64 + mt*16 + l16][ks*32 + q*8];
      #pragma unroll
      for (int nt = 0; nt < 4; nt++)
        bf[nt] = *(const short8*)&Bs[wc*64 + nt*16 + l16][ks*32 + q*8];
      #pragma unroll
      for (int mt = 0; mt < 4; mt++)
        #pragma unroll
        for (int nt = 0; nt < 4; nt++)
          acc[mt][nt] = __builtin_amdgcn_mfma_f32_16x16x32_bf16(af[mt], bf[nt], acc[mt][nt], 0, 0, 0);
    }
    __syncthreads();
  }

  #pragma unroll
  for (int mt = 0; mt < 4; mt++) {
    #pragma unroll
    for (int nt = 0; nt < 4; nt++) {
      const int col = n0 + wc*64 + nt*16 + l16;
      #pragma unroll
      for (int r = 0; r < 4; r++) {
        const int row = m0 + wr*64 + mt*16 + q*4 + r;
        op[(long)row*DIM + col] = acc[mt][nt][r] + vp[(long)row*DIM + col];
      }
    }
  }
}

// ---------------- fused fc + LN, MFMA, in place (verified) ----------------
__global__ __launch_bounds__(256) void fc_ln_mfma_kernel(
    float* __restrict__ X, const unsigned short* __restrict__ wT,
    const float* __restrict__ g, const float* __restrict__ b)
{
  __shared__ unsigned short As[32][72];
  __shared__ unsigned short Bs[512][72];
  __shared__ float red_s[4][32], red_q[4][32];
  __shared__ float gs[512], bs[512];
  const int tid = threadIdx.x;
  const long r0 = (long)blockIdx.x * 32;
  const int lane = tid & 63, wid = tid >> 6;
  const int q = lane >> 4, l16 = lane & 15;

  gs[tid] = g[tid]; gs[tid+256] = g[tid+256];
  bs[tid] = b[tid]; bs[tid+256] = b[tid+256];

  f32x4 acc[2][8] = {};

  for (int k0 = 0; k0 < DIM; k0 += 64) {
    {
      int r = tid >> 3, h = tid & 7;
      const float* src = &X[(r0+r)*DIM + k0 + h*8];
      float4 x0 = *(const float4*)src, x1 = *(const float4*)(src+4);
      unsigned int tmp[4] = {pack_bf2(x0.x,x0.y), pack_bf2(x0.z,x0.w),
                             pack_bf2(x1.x,x1.y), pack_bf2(x1.z,x1.w)};
      *(uint4*)&As[r][h*8] = *(uint4*)tmp;
    }
    #pragma unroll
    for (int e = tid; e < 4096; e += 256) {
      int n = e >> 3, j = e & 7;
      *(uint4*)&Bs[n][j*8] = *(const uint4*)&wT[(long)n*DIM + k0 + j*8];
    }
    __syncthreads();
    #pragma unroll
    for (int ks = 0; ks < 2; ks++) {
      short8 af[2], bf[8];
      #pragma unroll
      for (int mt = 0; mt < 2; mt++)
        af[mt] = *(const short8*)&As[mt*16 + l16][ks*32 + q*8];
      #pragma unroll
      for (int nt = 0; nt < 8; nt++)
        bf[nt] = *(const short8*)&Bs[wid*128 + nt*16 + l16][ks*32 + q*8];
      #pragma unroll
      for (int mt = 0; mt < 2; mt++)
        #pragma unroll
        for (int nt = 0; nt < 8; nt++)
          acc[mt][nt] = __builtin_amdgcn_mfma_f32_16x16x32_bf16(af[mt], bf[nt], acc[mt][nt], 0, 0, 0);
    }
    __syncthreads();
  }

  #pragma unroll
  for (int mt = 0; mt < 2; mt++) {
    #pragma unroll
    for (int r = 0; r < 4; r++) {
      float s = 0.f, z = 0.f;
      #pragma unroll
      for (int nt = 0; nt < 8; nt++) { float v = acc[mt][nt][r]; s += v; z += v*v; }
      #pragma unroll
      for (int o = 1; o < 16; o <<= 1) { s += __shfl_xor(s, o); z += __shfl_xor(z, o); }
      if (l16 == 0) { red_s[wid][mt*16 + q*4 + r] = s; red_q[wid][mt*16 + q*4 + r] = z; }
    }
  }
  __syncthreads();

  float mean[2][4], rstd[2][4];
  #pragma unroll
  for (int mt = 0; mt < 2; mt++)
    #pragma unroll
    for (int r = 0; r < 4; r++) {
      const int row = mt*16 + q*4 + r;
      float s = (red_s[0][row] + red_s[1][row]) + (red_s[2][row] + red_s[3][row]);
      float z = (red_q[0][row] + red_q[1][row]) + (red_q[2][row] + red_q[3][row]);
      float mu = s * (1.0f/DIM);
      float var = z * (1.0f/DIM) - mu*mu;
      var = fmaxf(var, 0.0f);
      mean[mt][r] = mu;
      rstd[mt][r] = rsqrtf(var + 1e-6f);
    }

  #pragma unroll
  for (int mt = 0; mt < 2; mt++) {
    #pragma unroll
    for (int nt = 0; nt < 8; nt++) {
      const int col = wid*128 + nt*16 + l16;
      const float gg = gs[col], bb = bs[col];
      #pragma unroll
      for (int r = 0; r < 4; r++) {
        const long row = r0 + mt*16 + q*4 + r;
        X[row*DIM + col] = (acc[mt][nt][r] - mean[mt][r])*rstd[mt][r]*gg + bb;
      }
    }
  }
}

extern "C" void kernel_launch(void* const* d_in, const int* in_sizes, int n_in,
                              void* d_out, int out_size, void* d_ws, size_t ws_size,
                              hipStream_t stream) {
  const float* q    = (const float*)d_in[0];
  const float* k    = (const float*)d_in[1];
  const float* v    = (const float*)d_in[2];
  const int*   mask = (const int*)d_in[3];
  const float* w_qs = (const float*)d_in[4];
  const float* w_ks = (const float*)d_in[5];
  const float* w_fc = (const float*)d_in[6];
  const float* ln_g = (const float*)d_in[7];
  const float* ln_b = (const float*)d_in[8];

  float* out   = (float*)d_out;                       // [B,N,DIM]
  float* attnF = out + (long)BB*SEQ*DIM;              // [B,N,N]: scores -> softmax in place

  // bf16 qp/kp live in the first 4MB of the out region (dead after scores kernel)
  unsigned short* qp = (unsigned short*)out;
  unsigned short* kp = qp + (long)BB*SEQ*DK;

  const long NN2 = (long)SEQ*SEQ;
  const long ND  = (long)SEQ*DIM;

  const size_t vT_bytes = (size_t)BB*DIM*SEQ*sizeof(unsigned short);   // 8.4 MB
  const size_t wT_bytes = (size_t)DIM*DIM*sizeof(unsigned short);      // 0.5 MB
  const bool fast  = (ws_size >= vT_bytes);                 // constant -> graph-safe
  const bool fast2 = (ws_size >= vT_bytes + wT_bytes);

  // 1+2) qp = bf16((q @ w_qs)/8), kp = bf16(k @ w_ks)   [MFMA, fused]
  proj_mfma_kernel<<<dim3(BB*SEQ/64, 2, 1), 256, 0, stream>>>(q, k, w_qs, w_ks, qp, kp);
  // 3) scores[b] = qp[b] @ kp[b]^T, mask==0 -> -1e9      [MFMA]
  scores_mfma_kernel<<<dim3(SEQ/128, SEQ/128, BB), 256, 0, stream>>>(qp, kp, mask, attnF);
  // 4) softmax in place
  softmax_kernel<<<dim3(BB*SEQ,1,1), 256, 0, stream>>>(attnF);
  // 5) out = attn @ v + v
  if (fast) {
    unsigned short* vT = (unsigned short*)d_ws;
    transpose_v_kernel<<<dim3(SEQ/64, DIM/64, BB), 256, 0, stream>>>(v, vT);
    attn_v_mfma_kernel<<<dim3(SEQ/128, DIM/128, BB), 256, 0, stream>>>(attnF, vT, v, out);
  } else {
    gemm_kernel<false,false,true,2><<<dim3(SEQ/128,DIM/128,BB), 256, 0, stream>>>(
        attnF, v, out, v, nullptr, SEQ, SEQ, DIM, DIM, NN2, ND, ND, ND, 0, 1.0f);
  }
  // 6+7) out = LayerNorm(out @ w_fc), fused, in place
  if (fast2) {
    unsigned short* wT = (unsigned short*)d_ws + (size_t)BB*DIM*SEQ;
    transpose_w_kernel<<<dim3(DIM/64, DIM/64, 1), 256, 0, stream>>>(w_fc, wT);
    fc_ln_mfma_kernel<<<dim3(BB*SEQ/32,1,1), 256, 0, stream>>>(out, wT, ln_g, ln_b);
  } else {
    fc_ln_kernel<<<dim3(BB*SEQ/32,1,1), 256, 0, stream>>>(out, w_fc, ln_g, ln_b);
  }
}

// Round 7
// 308.986 us; speedup vs baseline: 2.8489x; 1.1275x over previous
//
#include <hip/hip_runtime.h>
#include <hip/hip_bf16.h>

#define BB  4
#define SEQ 2048
#define DIM 512
#define DK  64

typedef __attribute__((ext_vector_type(8))) short short8;
typedef __attribute__((ext_vector_type(4))) float f32x4;

__device__ __forceinline__ unsigned int pack_bf2(float a, float b){
  __hip_bfloat16 ha = __float2bfloat16(a), hb = __float2bfloat16(b);
  unsigned short ua = __builtin_bit_cast(unsigned short, ha);
  unsigned short ub = __builtin_bit_cast(unsigned short, hb);
  return (unsigned int)ua | ((unsigned int)ub << 16);
}
__device__ __forceinline__ unsigned short to_bf(float a){
  return __builtin_bit_cast(unsigned short, __float2bfloat16(a));
}

// ---------------- Tiled f32 GEMM (verified; attn_v last-resort fallback) ----------------
template<bool BTRANS, bool MASKED, bool RESID, int NGRP>
__global__ __launch_bounds__(256) void gemm_kernel(
    const float* __restrict__ A, const float* __restrict__ Bm, float* __restrict__ C,
    const float* __restrict__ resid, const int* __restrict__ mask,
    int K, int lda, int ldb, int ldc,
    long sA, long sB, long sC, long sR, long sM, float scale)
{
  constexpr int TM = 128, TK = 32, TN = 64*NGRP;
  __shared__ float As[TK][TM+4];
  __shared__ float Bs[TK][TN+4];
  const int z = blockIdx.z;
  A += z*sA; Bm += z*sB; C += z*sC;
  const float* rp = nullptr; const int* mp = nullptr;
  if constexpr (RESID)  rp = resid + z*sR;
  if constexpr (MASKED) mp = mask  + z*sM;
  const int m0 = blockIdx.x*TM, n0 = blockIdx.y*TN;
  const int tid = threadIdx.x, tx = tid & 15, ty = tid >> 4;
  float acc[2][NGRP][4][4] = {};

  for (int k0 = 0; k0 < K; k0 += TK) {
    #pragma unroll
    for (int e = tid; e < TM*TK/4; e += 256) {
      int m = e >> 3, k4 = (e & 7) << 2;
      float4 a = *(const float4*)&A[(long)(m0+m)*lda + k0 + k4];
      As[k4+0][m] = a.x; As[k4+1][m] = a.y; As[k4+2][m] = a.z; As[k4+3][m] = a.w;
    }
    if constexpr (BTRANS) {
      #pragma unroll
      for (int e = tid; e < TN*TK/4; e += 256) {
        int n = e >> 3, k4 = (e & 7) << 2;
        float4 b = *(const float4*)&Bm[(long)(n0+n)*ldb + k0 + k4];
        Bs[k4+0][n] = b.x; Bs[k4+1][n] = b.y; Bs[k4+2][n] = b.z; Bs[k4+3][n] = b.w;
      }
    } else {
      constexpr int TN4 = TN/4;
      #pragma unroll
      for (int e = tid; e < TK*TN4; e += 256) {
        int kk = e / TN4, n4 = (e % TN4) << 2;
        *(float4*)&Bs[kk][n4] = *(const float4*)&Bm[(long)(k0+kk)*ldb + n0 + n4];
      }
    }
    __syncthreads();
    #pragma unroll
    for (int kk = 0; kk < TK; kk++) {
      float av[2][4];
      float bv[NGRP][4];
      *(float4*)av[0] = *(const float4*)&As[kk][ty*4];
      *(float4*)av[1] = *(const float4*)&As[kk][64 + ty*4];
      #pragma unroll
      for (int g = 0; g < NGRP; g++)
        *(float4*)bv[g] = *(const float4*)&Bs[kk][g*64 + tx*4];
      #pragma unroll
      for (int mg = 0; mg < 2; mg++)
        #pragma unroll
        for (int r = 0; r < 4; r++)
          #pragma unroll
          for (int g = 0; g < NGRP; g++)
            #pragma unroll
            for (int c = 0; c < 4; c++)
              acc[mg][g][r][c] = fmaf(av[mg][r], bv[g][c], acc[mg][g][r][c]);
    }
    __syncthreads();
  }

  #pragma unroll
  for (int mg = 0; mg < 2; mg++) {
    #pragma unroll
    for (int r = 0; r < 4; r++) {
      const int m = m0 + mg*64 + ty*4 + r;
      #pragma unroll
      for (int g = 0; g < NGRP; g++) {
        const int n = n0 + g*64 + tx*4;
        float4 v;
        v.x = acc[mg][g][r][0]*scale; v.y = acc[mg][g][r][1]*scale;
        v.z = acc[mg][g][r][2]*scale; v.w = acc[mg][g][r][3]*scale;
        if constexpr (RESID) {
          float4 rv = *(const float4*)&rp[(long)m*ldc + n];
          v.x += rv.x; v.y += rv.y; v.z += rv.z; v.w += rv.w;
        }
        if constexpr (MASKED) {
          int4 mv = *(const int4*)&mp[(long)m*ldc + n];
          if (!mv.x) v.x = -1e9f;
          if (!mv.y) v.y = -1e9f;
          if (!mv.z) v.z = -1e9f;
          if (!mv.w) v.w = -1e9f;
        }
        *(float4*)&C[(long)m*ldc + n] = v;
      }
    }
  }
}

// ---------------- fused q/k projection, MFMA, bf16 out (verified) ----------------
__global__ __launch_bounds__(256) void proj_mfma_kernel(
    const float* __restrict__ q, const float* __restrict__ k,
    const float* __restrict__ w_qs, const float* __restrict__ w_ks,
    unsigned short* __restrict__ qp, unsigned short* __restrict__ kp)
{
  __shared__ unsigned short As[64][72];
  __shared__ unsigned short Bs[64][72];
  const int z = blockIdx.y;
  const float* A = z ? k : q;
  const float* W = z ? w_ks : w_qs;
  unsigned short* D = z ? kp : qp;
  const float scale = z ? 1.0f : 0.125f;
  const long m0 = (long)blockIdx.x * 64;
  const int tid = threadIdx.x;
  const int lane = tid & 63, wid = tid >> 6;
  const int qq = lane >> 4, l16 = lane & 15;
  f32x4 acc[4] = {};

  for (int k0 = 0; k0 < DIM; k0 += 64) {
    {
      int r = tid >> 2, h = tid & 3;
      const float* src = &A[(m0+r)*DIM + k0 + h*16];
      float4 x0 = *(const float4*)src,     x1 = *(const float4*)(src+4),
             x2 = *(const float4*)(src+8), x3 = *(const float4*)(src+12);
      unsigned int tmp[8] = {pack_bf2(x0.x,x0.y),pack_bf2(x0.z,x0.w),
                             pack_bf2(x1.x,x1.y),pack_bf2(x1.z,x1.w),
                             pack_bf2(x2.x,x2.y),pack_bf2(x2.z,x2.w),
                             pack_bf2(x3.x,x3.y),pack_bf2(x3.z,x3.w)};
      *(uint4*)&As[r][h*16]   = ((uint4*)tmp)[0];
      *(uint4*)&As[r][h*16+8] = ((uint4*)tmp)[1];
    }
    {
      int kk = tid >> 2, n4 = (tid & 3) * 16;
      const float* src = &W[(long)(k0+kk)*DK + n4];
      float4 y0 = *(const float4*)src,     y1 = *(const float4*)(src+4),
             y2 = *(const float4*)(src+8), y3 = *(const float4*)(src+12);
      float yv[16] = {y0.x,y0.y,y0.z,y0.w, y1.x,y1.y,y1.z,y1.w,
                      y2.x,y2.y,y2.z,y2.w, y3.x,y3.y,y3.z,y3.w};
      #pragma unroll
      for (int j = 0; j < 16; j++)
        Bs[n4+j][kk] = to_bf(yv[j]);
    }
    __syncthreads();
    #pragma unroll
    for (int ks = 0; ks < 2; ks++) {
      short8 af = *(const short8*)&As[wid*16 + l16][ks*32 + qq*8];
      #pragma unroll
      for (int nt = 0; nt < 4; nt++) {
        short8 bf = *(const short8*)&Bs[nt*16 + l16][ks*32 + qq*8];
        acc[nt] = __builtin_amdgcn_mfma_f32_16x16x32_bf16(af, bf, acc[nt], 0, 0, 0);
      }
    }
    __syncthreads();
  }

  #pragma unroll
  for (int nt = 0; nt < 4; nt++) {
    const int col = nt*16 + l16;
    #pragma unroll
    for (int r = 0; r < 4; r++) {
      const long row = m0 + wid*16 + qq*4 + r;
      D[row*DK + col] = to_bf(acc[nt][r] * scale);
    }
  }
}

// ---------------- scores MFMA (pure): s[b] = qp[b]@kp[b]^T, f32 out ----------------
__global__ __launch_bounds__(256) void scores_mfma_kernel(
    const unsigned short* __restrict__ qp, const unsigned short* __restrict__ kp,
    float* __restrict__ scores)
{
  __shared__ unsigned short As[128][72];
  __shared__ unsigned short Bs[128][72];
  const int b = blockIdx.z;
  const unsigned short* ap = qp + (long)b*SEQ*DK;
  const unsigned short* bp = kp + (long)b*SEQ*DK;
  float* sp = scores + (long)b*SEQ*SEQ;
  const int m0 = blockIdx.x*128, n0 = blockIdx.y*128;
  const int tid = threadIdx.x;
  const int lane = tid & 63, wid = tid >> 6;
  const int wr = wid >> 1, wc = wid & 1;
  const int qq = lane >> 4, l16 = lane & 15;

  {
    int r = tid >> 1, h = tid & 1;
    const uint4* srcA = (const uint4*)&ap[(long)(m0+r)*DK + h*32];
    const uint4* srcB = (const uint4*)&bp[(long)(n0+r)*DK + h*32];
    uint4 a0=srcA[0],a1=srcA[1],a2=srcA[2],a3=srcA[3];
    uint4 b0=srcB[0],b1=srcB[1],b2=srcB[2],b3=srcB[3];
    *(uint4*)&As[r][h*32+ 0]=a0; *(uint4*)&As[r][h*32+ 8]=a1;
    *(uint4*)&As[r][h*32+16]=a2; *(uint4*)&As[r][h*32+24]=a3;
    *(uint4*)&Bs[r][h*32+ 0]=b0; *(uint4*)&Bs[r][h*32+ 8]=b1;
    *(uint4*)&Bs[r][h*32+16]=b2; *(uint4*)&Bs[r][h*32+24]=b3;
  }
  __syncthreads();

  f32x4 acc[4][4] = {};
  #pragma unroll
  for (int ks = 0; ks < 2; ks++) {
    short8 af[4], bf[4];
    #pragma unroll
    for (int mt = 0; mt < 4; mt++)
      af[mt] = *(const short8*)&As[wr*64 + mt*16 + l16][ks*32 + qq*8];
    #pragma unroll
    for (int nt = 0; nt < 4; nt++)
      bf[nt] = *(const short8*)&Bs[wc*64 + nt*16 + l16][ks*32 + qq*8];
    #pragma unroll
    for (int mt = 0; mt < 4; mt++)
      #pragma unroll
      for (int nt = 0; nt < 4; nt++)
        acc[mt][nt] = __builtin_amdgcn_mfma_f32_16x16x32_bf16(af[mt], bf[nt], acc[mt][nt], 0, 0, 0);
  }

  #pragma unroll
  for (int mt = 0; mt < 4; mt++) {
    #pragma unroll
    for (int nt = 0; nt < 4; nt++) {
      const int col = n0 + wc*64 + nt*16 + l16;
      #pragma unroll
      for (int r = 0; r < 4; r++) {
        const long row = m0 + wr*64 + mt*16 + qq*4 + r;
        sp[row*SEQ + col] = acc[mt][nt][r];
      }
    }
  }
}

// ---------------- softmax v2: mask + softmax in place, optional bf16 copy ----------------
// Reads raw scores + mask (coalesced int4), applies mask==0 -> -1e9, softmax,
// writes f32 attn in place; if attnB != nullptr also writes bf16 attn copy.
__global__ __launch_bounds__(256) void softmax_kernel2(
    float* __restrict__ attn, const int* __restrict__ mask,
    unsigned short* __restrict__ attnB)
{
  const long row = blockIdx.x;
  float* p = attn + row*SEQ;
  const int* mp = mask + row*SEQ;
  const int t = threadIdx.x;
  float4 a = ((const float4*)p)[t];
  float4 b = ((const float4*)p)[t + 256];
  int4 ma = ((const int4*)mp)[t];
  int4 mb = ((const int4*)mp)[t + 256];
  float f[8] = {a.x,a.y,a.z,a.w,b.x,b.y,b.z,b.w};
  if (!ma.x) f[0] = -1e9f;
  if (!ma.y) f[1] = -1e9f;
  if (!ma.z) f[2] = -1e9f;
  if (!ma.w) f[3] = -1e9f;
  if (!mb.x) f[4] = -1e9f;
  if (!mb.y) f[5] = -1e9f;
  if (!mb.z) f[6] = -1e9f;
  if (!mb.w) f[7] = -1e9f;
  float M = f[0];
  #pragma unroll
  for (int i = 1; i < 8; i++) M = fmaxf(M, f[i]);
  #pragma unroll
  for (int o = 1; o < 64; o <<= 1) M = fmaxf(M, __shfl_xor(M, o));
  __shared__ float r1[4], r2[4];
  if ((t & 63) == 0) r1[t >> 6] = M;
  __syncthreads();
  M = fmaxf(fmaxf(r1[0], r1[1]), fmaxf(r1[2], r1[3]));
  float s = 0.f;
  #pragma unroll
  for (int i = 0; i < 8; i++) { f[i] = __expf(f[i] - M); s += f[i]; }
  #pragma unroll
  for (int o = 1; o < 64; o <<= 1) s += __shfl_xor(s, o);
  if ((t & 63) == 0) r2[t >> 6] = s;
  __syncthreads();
  s = (r2[0] + r2[1]) + (r2[2] + r2[3]);
  const float inv = 1.0f / s;
  #pragma unroll
  for (int i = 0; i < 8; i++) f[i] *= inv;
  a.x = f[0]; a.y = f[1]; a.z = f[2]; a.w = f[3];
  b.x = f[4]; b.y = f[5]; b.z = f[6]; b.w = f[7];
  ((float4*)p)[t] = a;
  ((float4*)p)[t + 256] = b;
  if (attnB) {
    unsigned short* pb = attnB + row*SEQ;
    uint2 w0 = { pack_bf2(f[0], f[1]), pack_bf2(f[2], f[3]) };
    uint2 w1 = { pack_bf2(f[4], f[5]), pack_bf2(f[6], f[7]) };
    *(uint2*)&pb[t*4]        = w0;
    *(uint2*)&pb[1024 + t*4] = w1;
  }
}

// ---------------- attn_v v2: out[b] = attn[b]@v[b] + v[b], bf16 attn input ----------------
// 128x64 tiles -> 512 blocks (2 blocks/CU). Pure uint4 staging, no repack.
// 4 waves: wave w owns rows [w*32, w*32+32) x 64 cols: 2 mt x 4 nt of 16x16x32.
__global__ __launch_bounds__(256) void attn_v_mfma2_kernel(
    const unsigned short* __restrict__ attnB, const unsigned short* __restrict__ vT,
    const float* __restrict__ v, float* __restrict__ out)
{
  __shared__ unsigned short As[128][72];
  __shared__ unsigned short Bs[64][72];
  const int b = blockIdx.z;
  const unsigned short* ap = attnB + (long)b*SEQ*SEQ;
  const unsigned short* bp = vT + (long)b*DIM*SEQ;
  const float* vp = v + (long)b*SEQ*DIM;
  float* op = out + (long)b*SEQ*DIM;
  const int m0 = blockIdx.x*128, n0 = blockIdx.y*64;
  const int tid = threadIdx.x;
  const int lane = tid & 63, wid = tid >> 6;
  const int q = lane >> 4, l16 = lane & 15;

  f32x4 acc[2][4] = {};

  for (int k0 = 0; k0 < SEQ; k0 += 64) {
    { // A: 128 rows x 64 k bf16, 2 threads/row x 64B
      int r = tid >> 1, h = tid & 1;
      const uint4* src = (const uint4*)&ap[(long)(m0+r)*SEQ + k0 + h*32];
      uint4 a0 = src[0], a1 = src[1], a2 = src[2], a3 = src[3];
      *(uint4*)&As[r][h*32 +  0] = a0;
      *(uint4*)&As[r][h*32 +  8] = a1;
      *(uint4*)&As[r][h*32 + 16] = a2;
      *(uint4*)&As[r][h*32 + 24] = a3;
    }
    { // B: 64 n-rows x 64 k bf16, 4 threads/row x 32B
      int n = tid >> 2, h = tid & 3;
      const uint4* src = (const uint4*)&bp[(long)(n0+n)*SEQ + k0 + h*16];
      uint4 b0 = src[0], b1 = src[1];
      *(uint4*)&Bs[n][h*16 + 0] = b0;
      *(uint4*)&Bs[n][h*16 + 8] = b1;
    }
    __syncthreads();
    #pragma unroll
    for (int ks = 0; ks < 2; ks++) {
      short8 af[2], bf[4];
      #pragma unroll
      for (int mt = 0; mt < 2; mt++)
        af[mt] = *(const short8*)&As[wid*32 + mt*16 + l16][ks*32 + q*8];
      #pragma unroll
      for (int nt = 0; nt < 4; nt++)
        bf[nt] = *(const short8*)&Bs[nt*16 + l16][ks*32 + q*8];
      #pragma unroll
      for (int mt = 0; mt < 2; mt++)
        #pragma unroll
        for (int nt = 0; nt < 4; nt++)
          acc[mt][nt] = __builtin_amdgcn_mfma_f32_16x16x32_bf16(af[mt], bf[nt], acc[mt][nt], 0, 0, 0);
    }
    __syncthreads();
  }

  #pragma unroll
  for (int mt = 0; mt < 2; mt++) {
    #pragma unroll
    for (int nt = 0; nt < 4; nt++) {
      const int col = n0 + nt*16 + l16;
      #pragma unroll
      for (int r = 0; r < 4; r++) {
        const int row = m0 + wid*32 + mt*16 + q*4 + r;
        op[(long)row*DIM + col] = acc[mt][nt][r] + vp[(long)row*DIM + col];
      }
    }
  }
}

// ---------------- pass 5 MFMA, f32-attn input (verified; mid fallback) ----------------
__global__ __launch_bounds__(256) void attn_v_mfma_kernel(
    const float* __restrict__ attn, const unsigned short* __restrict__ vT,
    const float* __restrict__ v, float* __restrict__ out)
{
  __shared__ unsigned short As[128][72];
  __shared__ unsigned short Bs[128][72];
  const int b = blockIdx.z;
  const float* ap = attn + (long)b*SEQ*SEQ;
  const unsigned short* bp = vT + (long)b*DIM*SEQ;
  const float* vp = v + (long)b*SEQ*DIM;
  float* op = out + (long)b*SEQ*DIM;
  const int m0 = blockIdx.x*128, n0 = blockIdx.y*128;
  const int tid = threadIdx.x;
  const int lane = tid & 63, wid = tid >> 6;
  const int wr = wid >> 1, wc = wid & 1;
  const int q = lane >> 4, l16 = lane & 15;

  f32x4 acc[4][4] = {};

  for (int k0 = 0; k0 < SEQ; k0 += 64) {
    {
      int r = tid >> 1, h = tid & 1;
      const float4* src = (const float4*)&ap[(long)(m0+r)*SEQ + k0 + h*32];
      unsigned int tmp[16];
      #pragma unroll
      for (int j = 0; j < 8; j++) {
        float4 x = src[j];
        tmp[2*j]   = pack_bf2(x.x, x.y);
        tmp[2*j+1] = pack_bf2(x.z, x.w);
      }
      #pragma unroll
      for (int j = 0; j < 4; j++)
        *(uint4*)&As[r][h*32 + 8*j] = ((const uint4*)tmp)[j];
    }
    {
      int n = tid >> 1, h = tid & 1;
      const uint4* src = (const uint4*)&bp[(long)(n0+n)*SEQ + k0 + h*32];
      uint4 b0 = src[0], b1 = src[1], b2 = src[2], b3 = src[3];
      *(uint4*)&Bs[n][h*32 +  0] = b0;
      *(uint4*)&Bs[n][h*32 +  8] = b1;
      *(uint4*)&Bs[n][h*32 + 16] = b2;
      *(uint4*)&Bs[n][h*32 + 24] = b3;
    }
    __syncthreads();
    #pragma unroll
    for (int ks = 0; ks < 2; ks++) {
      short8 af[4], bf[4];
      #pragma unroll
      for (int mt = 0; mt < 4; mt++)
        af[mt] = *(const short8*)&As[wr*64 + mt*16 + l16][ks*32 + q*8];
      #pragma unroll
      for (int nt = 0; nt < 4; nt++)
        bf[nt] = *(const short8*)&Bs[wc*64 + nt*16 + l16][ks*32 + q*8];
      #pragma unroll
      for (int mt = 0; mt < 4; mt++)
        #pragma unroll
        for (int nt = 0; nt < 4; nt++)
          acc[mt][nt] = __builtin_amdgcn_mfma_f32_16x16x32_bf16(af[mt], bf[nt], acc[mt][nt], 0, 0, 0);
    }
    __syncthreads();
  }

  #pragma unroll
  for (int mt = 0; mt < 4; mt++) {
    #pragma unroll
    for (int nt = 0; nt < 4; nt++) {
      const int col = n0 + wc*64 + nt*16 + l16;
      #pragma unroll
      for (int r = 0; r < 4; r++) {
        const int row = m0 + wr*64 + mt*16 + q*4 + r;
        op[(long)row*DIM + col] = acc[mt][nt][r] + vp[(long)row*DIM + col];
      }
    }
  }
}

// ---------------- fused fc + LayerNorm in place (VALU fallback, verified) ----------------
__global__ __launch_bounds__(256) void fc_ln_kernel(
    float* __restrict__ X, const float* __restrict__ W,
    const float* __restrict__ g, const float* __restrict__ b)
{
  __shared__ float As[32][32+4];
  __shared__ float Bs[32][512+4];
  const int tid = threadIdx.x;
  const long r0 = (long)blockIdx.x * 32;
  const int tx = tid & 63, ty = tid >> 6;
  float acc[8][8] = {};

  for (int k0 = 0; k0 < DIM; k0 += 32) {
    {
      int m = tid >> 3, k4 = (tid & 7) << 2;
      float4 a = *(const float4*)&X[(r0+m)*DIM + k0 + k4];
      As[k4+0][m] = a.x; As[k4+1][m] = a.y; As[k4+2][m] = a.z; As[k4+3][m] = a.w;
    }
    #pragma unroll
    for (int e = tid; e < 32*128; e += 256) {
      int kk = e >> 7, n4 = (e & 127) << 2;
      *(float4*)&Bs[kk][n4] = *(const float4*)&W[(long)(k0+kk)*DIM + n4];
    }
    __syncthreads();
    #pragma unroll
    for (int kk = 0; kk < 32; kk++) {
      float a[8], bb[8];
      *(float4*)&a[0]  = *(const float4*)&As[kk][ty*8];
      *(float4*)&a[4]  = *(const float4*)&As[kk][ty*8+4];
      *(float4*)&bb[0] = *(const float4*)&Bs[kk][tx*8];
      *(float4*)&bb[4] = *(const float4*)&Bs[kk][tx*8+4];
      #pragma unroll
      for (int r = 0; r < 8; r++)
        #pragma unroll
        for (int c = 0; c < 8; c++)
          acc[r][c] = fmaf(a[r], bb[c], acc[r][c]);
    }
    __syncthreads();
  }

  float gv[8], bv[8];
  *(float4*)&gv[0] = *(const float4*)&g[tx*8];
  *(float4*)&gv[4] = *(const float4*)&g[tx*8+4];
  *(float4*)&bv[0] = *(const float4*)&b[tx*8];
  *(float4*)&bv[4] = *(const float4*)&b[tx*8+4];

  #pragma unroll
  for (int r = 0; r < 8; r++) {
    float s = 0.f, sq = 0.f;
    #pragma unroll
    for (int c = 0; c < 8; c++) { s += acc[r][c]; sq += acc[r][c]*acc[r][c]; }
    #pragma unroll
    for (int o = 1; o < 64; o <<= 1) { s += __shfl_xor(s, o); sq += __shfl_xor(sq, o); }
    const float mean = s * (1.0f/DIM);
    float var = sq * (1.0f/DIM) - mean*mean;
    var = fmaxf(var, 0.0f);
    const float rs = rsqrtf(var + 1e-6f);
    float o0[8];
    #pragma unroll
    for (int c = 0; c < 8; c++) o0[c] = (acc[r][c] - mean)*rs*gv[c] + bv[c];
    float* dst = &X[(r0 + ty*8 + r)*DIM + tx*8];
    *(float4*)&dst[0] = *(const float4*)&o0[0];
    *(float4*)&dst[4] = *(const float4*)&o0[4];
  }
}

// ---------------- v transpose: vT[b][n][k] = bf16(v[b][k][n]) ----------------
__global__ __launch_bounds__(256) void transpose_v_kernel(
    const float* __restrict__ v, unsigned short* __restrict__ vT)
{
  __shared__ float T[64][65];
  const int b = blockIdx.z;
  const int k0 = blockIdx.x*64, n0 = blockIdx.y*64;
  const float* vb = v + (long)b*SEQ*DIM;
  unsigned short* tb = vT + (long)b*DIM*SEQ;
  const int t = threadIdx.x;
  {
    int kk = t >> 2, nq = (t & 3)*16;
    const float4* src = (const float4*)&vb[(long)(k0+kk)*DIM + n0 + nq];
    #pragma unroll
    for (int j = 0; j < 4; j++) {
      float4 x = src[j];
      T[kk][nq+4*j+0] = x.x; T[kk][nq+4*j+1] = x.y;
      T[kk][nq+4*j+2] = x.z; T[kk][nq+4*j+3] = x.w;
    }
  }
  __syncthreads();
  {
    int n = t >> 2, kq = (t & 3)*16;
    unsigned int w[8];
    #pragma unroll
    for (int j = 0; j < 8; j++)
      w[j] = pack_bf2(T[kq+2*j][n], T[kq+2*j+1][n]);
    unsigned short* dst = &tb[(long)(n0+n)*SEQ + k0 + kq];
    *(uint4*)&dst[0] = *(uint4*)&w[0];
    *(uint4*)&dst[8] = *(uint4*)&w[4];
  }
}

// ---------------- w_fc transpose: wT[n][k] = bf16(w_fc[k][n]) ----------------
__global__ __launch_bounds__(256) void transpose_w_kernel(
    const float* __restrict__ w, unsigned short* __restrict__ wT)
{
  __shared__ float T[64][65];
  const int k0 = blockIdx.x*64, n0 = blockIdx.y*64;
  const int t = threadIdx.x;
  {
    int kk = t >> 2, nq = (t & 3)*16;
    const float4* src = (const float4*)&w[(long)(k0+kk)*DIM + n0 + nq];
    #pragma unroll
    for (int j = 0; j < 4; j++) {
      float4 x = src[j];
      T[kk][nq+4*j+0] = x.x; T[kk][nq+4*j+1] = x.y;
      T[kk][nq+4*j+2] = x.z; T[kk][nq+4*j+3] = x.w;
    }
  }
  __syncthreads();
  {
    int n = t >> 2, kq = (t & 3)*16;
    unsigned int wv[8];
    #pragma unroll
    for (int j = 0; j < 8; j++)
      wv[j] = pack_bf2(T[kq+2*j][n], T[kq+2*j+1][n]);
    unsigned short* dst = &wT[(long)(n0+n)*DIM + k0 + kq];
    *(uint4*)&dst[0] = *(uint4*)&wv[0];
    *(uint4*)&dst[8] = *(uint4*)&wv[4];
  }
}

// ---------------- fused fc + LN, MFMA, in place (verified) ----------------
__global__ __launch_bounds__(256) void fc_ln_mfma_kernel(
    float* __restrict__ X, const unsigned short* __restrict__ wT,
    const float* __restrict__ g, const float* __restrict__ b)
{
  __shared__ unsigned short As[32][72];
  __shared__ unsigned short Bs[512][72];
  __shared__ float red_s[4][32], red_q[4][32];
  __shared__ float gs[512], bs[512];
  const int tid = threadIdx.x;
  const long r0 = (long)blockIdx.x * 32;
  const int lane = tid & 63, wid = tid >> 6;
  const int q = lane >> 4, l16 = lane & 15;

  gs[tid] = g[tid]; gs[tid+256] = g[tid+256];
  bs[tid] = b[tid]; bs[tid+256] = b[tid+256];

  f32x4 acc[2][8] = {};

  for (int k0 = 0; k0 < DIM; k0 += 64) {
    {
      int r = tid >> 3, h = tid & 7;
      const float* src = &X[(r0+r)*DIM + k0 + h*8];
      float4 x0 = *(const float4*)src, x1 = *(const float4*)(src+4);
      unsigned int tmp[4] = {pack_bf2(x0.x,x0.y), pack_bf2(x0.z,x0.w),
                             pack_bf2(x1.x,x1.y), pack_bf2(x1.z,x1.w)};
      *(uint4*)&As[r][h*8] = *(uint4*)tmp;
    }
    #pragma unroll
    for (int e = tid; e < 4096; e += 256) {
      int n = e >> 3, j = e & 7;
      *(uint4*)&Bs[n][j*8] = *(const uint4*)&wT[(long)n*DIM + k0 + j*8];
    }
    __syncthreads();
    #pragma unroll
    for (int ks = 0; ks < 2; ks++) {
      short8 af[2], bf[8];
      #pragma unroll
      for (int mt = 0; mt < 2; mt++)
        af[mt] = *(const short8*)&As[mt*16 + l16][ks*32 + q*8];
      #pragma unroll
      for (int nt = 0; nt < 8; nt++)
        bf[nt] = *(const short8*)&Bs[wid*128 + nt*16 + l16][ks*32 + q*8];
      #pragma unroll
      for (int mt = 0; mt < 2; mt++)
        #pragma unroll
        for (int nt = 0; nt < 8; nt++)
          acc[mt][nt] = __builtin_amdgcn_mfma_f32_16x16x32_bf16(af[mt], bf[nt], acc[mt][nt], 0, 0, 0);
    }
    __syncthreads();
  }

  #pragma unroll
  for (int mt = 0; mt < 2; mt++) {
    #pragma unroll
    for (int r = 0; r < 4; r++) {
      float s = 0.f, z = 0.f;
      #pragma unroll
      for (int nt = 0; nt < 8; nt++) { float v = acc[mt][nt][r]; s += v; z += v*v; }
      #pragma unroll
      for (int o = 1; o < 16; o <<= 1) { s += __shfl_xor(s, o); z += __shfl_xor(z, o); }
      if (l16 == 0) { red_s[wid][mt*16 + q*4 + r] = s; red_q[wid][mt*16 + q*4 + r] = z; }
    }
  }
  __syncthreads();

  float mean[2][4], rstd[2][4];
  #pragma unroll
  for (int mt = 0; mt < 2; mt++)
    #pragma unroll
    for (int r = 0; r < 4; r++) {
      const int row = mt*16 + q*4 + r;
      float s = (red_s[0][row] + red_s[1][row]) + (red_s[2][row] + red_s[3][row]);
      float z = (red_q[0][row] + red_q[1][row]) + (red_q[2][row] + red_q[3][row]);
      float mu = s * (1.0f/DIM);
      float var = z * (1.0f/DIM) - mu*mu;
      var = fmaxf(var, 0.0f);
      mean[mt][r] = mu;
      rstd[mt][r] = rsqrtf(var + 1e-6f);
    }

  #pragma unroll
  for (int mt = 0; mt < 2; mt++) {
    #pragma unroll
    for (int nt = 0; nt < 8; nt++) {
      const int col = wid*128 + nt*16 + l16;
      const float gg = gs[col], bb = bs[col];
      #pragma unroll
      for (int r = 0; r < 4; r++) {
        const long row = r0 + mt*16 + q*4 + r;
        X[row*DIM + col] = (acc[mt][nt][r] - mean[mt][r])*rstd[mt][r]*gg + bb;
      }
    }
  }
}

extern "C" void kernel_launch(void* const* d_in, const int* in_sizes, int n_in,
                              void* d_out, int out_size, void* d_ws, size_t ws_size,
                              hipStream_t stream) {
  const float* q    = (const float*)d_in[0];
  const float* k    = (const float*)d_in[1];
  const float* v    = (const float*)d_in[2];
  const int*   mask = (const int*)d_in[3];
  const float* w_qs = (const float*)d_in[4];
  const float* w_ks = (const float*)d_in[5];
  const float* w_fc = (const float*)d_in[6];
  const float* ln_g = (const float*)d_in[7];
  const float* ln_b = (const float*)d_in[8];

  float* out   = (float*)d_out;                       // [B,N,DIM]
  float* attnF = out + (long)BB*SEQ*DIM;              // [B,N,N]: scores -> softmax in place

  unsigned short* qp = (unsigned short*)out;          // bf16, first 4MB of out region
  unsigned short* kp = qp + (long)BB*SEQ*DK;

  const long NN2 = (long)SEQ*SEQ;
  const long ND  = (long)SEQ*DIM;

  // ws tiers (all constant per process -> graph-safe):
  const size_t vT_bytes    = (size_t)BB*DIM*SEQ*2;    // 8.4 MB
  const size_t wT_bytes    = (size_t)DIM*DIM*2;       // 0.5 MB
  const size_t attnB_bytes = (size_t)BB*SEQ*SEQ*2;    // 33.6 MB
  const bool fast  = (ws_size >= vT_bytes);                           // known true (r4)
  const bool fast2 = (ws_size >= vT_bytes + wT_bytes);                // known true (r5)
  const bool fast3 = (ws_size >= vT_bytes + wT_bytes + attnB_bytes);  // probe this round

  unsigned short* vT    = (unsigned short*)d_ws;
  unsigned short* wT    = vT + (size_t)BB*DIM*SEQ;
  unsigned short* attnB = wT + (size_t)DIM*DIM;

  // 1+2) qp = bf16((q @ w_qs)/8), kp = bf16(k @ w_ks)   [MFMA, fused]
  proj_mfma_kernel<<<dim3(BB*SEQ/64, 2, 1), 256, 0, stream>>>(q, k, w_qs, w_ks, qp, kp);
  // 3) raw scores[b] = qp[b] @ kp[b]^T (mask deferred to softmax)
  scores_mfma_kernel<<<dim3(SEQ/128, SEQ/128, BB), 256, 0, stream>>>(qp, kp, attnF);
  // 4) mask + softmax in place (+ bf16 copy if ws allows)
  softmax_kernel2<<<dim3(BB*SEQ,1,1), 256, 0, stream>>>(
      attnF, mask, fast3 ? attnB : (unsigned short*)nullptr);
  // 5) out = attn @ v + v
  if (fast) {
    transpose_v_kernel<<<dim3(SEQ/64, DIM/64, BB), 256, 0, stream>>>(v, vT);
    if (fast3) {
      attn_v_mfma2_kernel<<<dim3(SEQ/128, DIM/64, BB), 256, 0, stream>>>(attnB, vT, v, out);
    } else {
      attn_v_mfma_kernel<<<dim3(SEQ/128, DIM/128, BB), 256, 0, stream>>>(attnF, vT, v, out);
    }
  } else {
    gemm_kernel<false,false,true,2><<<dim3(SEQ/128,DIM/128,BB), 256, 0, stream>>>(
        attnF, v, out, v, nullptr, SEQ, SEQ, DIM, DIM, NN2, ND, ND, ND, 0, 1.0f);
  }
  // 6+7) out = LayerNorm(out @ w_fc), fused, in place
  if (fast2) {
    transpose_w_kernel<<<dim3(DIM/64, DIM/64, 1), 256, 0, stream>>>(w_fc, wT);
    fc_ln_mfma_kernel<<<dim3(BB*SEQ/32,1,1), 256, 0, stream>>>(out, wT, ln_g, ln_b);
  } else {
    fc_ln_kernel<<<dim3(BB*SEQ/32,1,1), 256, 0, stream>>>(out, w_fc, ln_g, ln_b);
  }
}